// Round 2
// baseline (1044.582 us; speedup 1.0000x reference)
//
#include <hip/hip_runtime.h>

static constexpr int D = 128;

// ---------------- CSR build ----------------
// NOTE: harness delivers integer inputs as int32 (edge_index is [2,E] int32).

__global__ void count_kernel(const int* __restrict__ edges, int E,
                             int* __restrict__ deg) {
  int e = blockIdx.x * blockDim.x + threadIdx.x;
  if (e >= E) return;
  int dst = edges[(size_t)E + e];
  atomicAdd(&deg[dst], 1);
}

__global__ void scan_kernel(const int* __restrict__ deg, int* __restrict__ row_start,
                            int* __restrict__ cursor, int N) {
  __shared__ int part[1024];
  int t = threadIdx.x;
  int chunk = (N + 1023) >> 10;
  int lo = t * chunk;
  int hi = min(lo + chunk, N);
  int s = 0;
  for (int i = lo; i < hi; ++i) s += deg[i];
  part[t] = s;
  __syncthreads();
  for (int off = 1; off < 1024; off <<= 1) {
    int v = (t >= off) ? part[t - off] : 0;
    __syncthreads();
    part[t] += v;
    __syncthreads();
  }
  int run = (t > 0) ? part[t - 1] : 0;
  for (int i = lo; i < hi; ++i) {
    row_start[i] = run;
    cursor[i] = run;
    run += deg[i];
  }
  if (t == 1023) row_start[N] = run;
}

__global__ void fill_kernel(const int* __restrict__ edges, int E,
                            int* __restrict__ cursor, int* __restrict__ csr_src) {
  int e = blockIdx.x * blockDim.x + threadIdx.x;
  if (e >= E) return;
  int src = edges[e];
  int dst = edges[(size_t)E + e];
  int pos = atomicAdd(&cursor[dst], 1);
  csr_src[pos] = src;
}

// ---------------- mean aggregation (pull, one wave per node) ----------------

__global__ __launch_bounds__(256) void agg_kernel(
    const float* __restrict__ xin, const int* __restrict__ row_start,
    const int* __restrict__ csr_src, float* __restrict__ agg, int N) {
  int wid = (blockIdx.x * blockDim.x + threadIdx.x) >> 6;
  int lane = threadIdx.x & 63;
  if (wid >= N) return;
  int r0 = row_start[wid];
  int r1 = row_start[wid + 1];
  float ax = 0.f, ay = 0.f;
  for (int base = r0; base < r1; base += 64) {
    int cnt = min(64, r1 - base);
    int idx = (lane < cnt) ? csr_src[base + lane] : 0;
    for (int j = 0; j < cnt; ++j) {
      int s = __shfl(idx, j);
      const float2 v = *reinterpret_cast<const float2*>(xin + (size_t)s * D + lane * 2);
      ax += v.x;
      ay += v.y;
    }
  }
  float inv = 1.0f / (float)max(r1 - r0, 1);
  float2 o;
  o.x = ax * inv;
  o.y = ay * inv;
  *reinterpret_cast<float2*>(agg + (size_t)wid * D + lane * 2) = o;
}

// ---------------- fused GEMM: out = normalize(agg@Wl + b + x@Wr), opt ReLU ----------------
// A = [agg | x]  (K=256), B = [Wl ; Wr]. BM=64, BN=128(full), K chunked by 64.

__global__ __launch_bounds__(256) void sage_gemm_kernel(
    const float* __restrict__ agg, const float* __restrict__ xin,
    const float* __restrict__ Wl, const float* __restrict__ Wr,
    const float* __restrict__ bias, float* __restrict__ out,
    int N, int relu) {
  __shared__ float A_lds[64][68];   // +4 pad
  __shared__ float B_lds[64][128];
  const int tid = threadIdx.x;
  const int tn = tid & 15;   // 16 output-groups of 8
  const int tm = tid >> 4;   // 16 node-groups of 4
  const int block_row = blockIdx.x * 64;

  float acc[4][8];
#pragma unroll
  for (int i = 0; i < 4; ++i)
#pragma unroll
    for (int j = 0; j < 8; ++j) acc[i][j] = 0.f;

  for (int kc = 0; kc < 4; ++kc) {
    __syncthreads();
    // stage A: 64 rows x 64 k of [agg|x]
#pragma unroll
    for (int t = 0; t < 4; ++t) {
      int f = tid + t * 256;
      int row = f >> 4;
      int col = (f & 15) * 4;
      int gk = kc * 64 + col;
      int n = min(block_row + row, N - 1);
      const float* srcp = (gk < D) ? (agg + (size_t)n * D + gk)
                                   : (xin + (size_t)n * D + (gk - D));
      float4 v = *reinterpret_cast<const float4*>(srcp);
      *reinterpret_cast<float4*>(&A_lds[row][col]) = v;
    }
    // stage B: 64 k-rows x 128 outs of [Wl;Wr]
#pragma unroll
    for (int t = 0; t < 8; ++t) {
      int f = tid + t * 256;
      int kk = f >> 5;
      int col = (f & 31) * 4;
      int gk = kc * 64 + kk;
      const float* srcp = (gk < D) ? (Wl + (size_t)gk * D + col)
                                   : (Wr + (size_t)(gk - D) * D + col);
      float4 v = *reinterpret_cast<const float4*>(srcp);
      *reinterpret_cast<float4*>(&B_lds[kk][col]) = v;
    }
    __syncthreads();
#pragma unroll
    for (int k4 = 0; k4 < 16; ++k4) {
      float4 av[4];
#pragma unroll
      for (int i = 0; i < 4; ++i)
        av[i] = *reinterpret_cast<const float4*>(&A_lds[tm * 4 + i][k4 * 4]);
#pragma unroll
      for (int u = 0; u < 4; ++u) {
        float4 b0 = *reinterpret_cast<const float4*>(&B_lds[k4 * 4 + u][tn * 8]);
        float4 b1 = *reinterpret_cast<const float4*>(&B_lds[k4 * 4 + u][tn * 8 + 4]);
        float bv0 = b0.x, bv1 = b0.y, bv2 = b0.z, bv3 = b0.w;
        float bv4 = b1.x, bv5 = b1.y, bv6 = b1.z, bv7 = b1.w;
#pragma unroll
        for (int i = 0; i < 4; ++i) {
          float a = (u == 0) ? av[i].x : (u == 1) ? av[i].y : (u == 2) ? av[i].z : av[i].w;
          acc[i][0] += a * bv0;
          acc[i][1] += a * bv1;
          acc[i][2] += a * bv2;
          acc[i][3] += a * bv3;
          acc[i][4] += a * bv4;
          acc[i][5] += a * bv5;
          acc[i][6] += a * bv6;
          acc[i][7] += a * bv7;
        }
      }
    }
  }

  // epilogue: bias + row L2-normalize (row spread over 16 lanes) + optional ReLU
  float bv[8];
#pragma unroll
  for (int j = 0; j < 8; ++j) bv[j] = bias[tn * 8 + j];
#pragma unroll
  for (int i = 0; i < 4; ++i) {
    float v[8];
    float ss = 0.f;
#pragma unroll
    for (int j = 0; j < 8; ++j) {
      v[j] = acc[i][j] + bv[j];
      ss += v[j] * v[j];
    }
    ss += __shfl_xor(ss, 1);
    ss += __shfl_xor(ss, 2);
    ss += __shfl_xor(ss, 4);
    ss += __shfl_xor(ss, 8);
    float scale = 1.0f / fmaxf(sqrtf(ss), 1e-12f);
    int gn = block_row + tm * 4 + i;
    if (gn < N) {
      float o[8];
#pragma unroll
      for (int j = 0; j < 8; ++j) {
        o[j] = v[j] * scale;
        if (relu) o[j] = fmaxf(o[j], 0.f);
      }
      float4 w0, w1;
      w0.x = o[0]; w0.y = o[1]; w0.z = o[2]; w0.w = o[3];
      w1.x = o[4]; w1.y = o[5]; w1.z = o[6]; w1.w = o[7];
      float* dst = out + (size_t)gn * D + tn * 8;
      *reinterpret_cast<float4*>(dst) = w0;
      *reinterpret_cast<float4*>(dst + 4) = w1;
    }
  }
}

// ---------------- launch ----------------

extern "C" void kernel_launch(void* const* d_in, const int* in_sizes, int n_in,
                              void* d_out, int out_size, void* d_ws, size_t ws_size,
                              hipStream_t stream) {
  const float* x = (const float*)d_in[0];
  const int* edges = (const int*)d_in[1];  // int32 per harness convention
  const float* W1l = (const float*)d_in[2];
  const float* b1 = (const float*)d_in[3];
  const float* W1r = (const float*)d_in[4];
  const float* W2l = (const float*)d_in[5];
  const float* b2 = (const float*)d_in[6];
  const float* W2r = (const float*)d_in[7];
  float* out = (float*)d_out;

  const int N = in_sizes[0] / D;  // 100000
  const int E = in_sizes[1] / 2;  // 1600000

  char* ws = (char*)d_ws;
  float* agg = (float*)ws;                              // N*D f32 = 51.2 MB
  int* deg = (int*)(ws + (size_t)N * D * sizeof(float));
  int* row_start = deg + N;                             // N+1
  int* cursor = row_start + (N + 1);                    // N
  int* csr_src = cursor + N;                            // E

  hipMemsetAsync(deg, 0, (size_t)N * sizeof(int), stream);
  count_kernel<<<(E + 255) / 256, 256, 0, stream>>>(edges, E, deg);
  scan_kernel<<<1, 1024, 0, stream>>>(deg, row_start, cursor, N);
  fill_kernel<<<(E + 255) / 256, 256, 0, stream>>>(edges, E, cursor, csr_src);

  // layer 1: h = relu(normalize(mean@W1l + b1 + x@W1r)) -> d_out (as scratch h)
  agg_kernel<<<(N + 3) / 4, 256, 0, stream>>>(x, row_start, csr_src, agg, N);
  sage_gemm_kernel<<<(N + 63) / 64, 256, 0, stream>>>(agg, x, W1l, W1r, b1, out, N, 1);

  // layer 2: out = normalize(mean(h)@W2l + b2 + h@W2r), in-place over h
  agg_kernel<<<(N + 3) / 4, 256, 0, stream>>>(out, row_start, csr_src, agg, N);
  sage_gemm_kernel<<<(N + 63) / 64, 256, 0, stream>>>(agg, out, W2l, W2r, b2, out, N, 0);
}

// Round 3
// 960.398 us; speedup vs baseline: 1.0877x; 1.0877x over previous
//
#include <hip/hip_runtime.h>

static constexpr int D = 128;
static constexpr int CHUNK = 2048;  // elements per block in the decomposed scan

// ---------------- CSR build ----------------
// Harness delivers integer inputs as int32 (edge_index is [2,E] int32).

__global__ void count_kernel(const int* __restrict__ edges, int E,
                             int* __restrict__ deg) {
  int e = blockIdx.x * blockDim.x + threadIdx.x;
  if (e >= E) return;
  int dst = edges[(size_t)E + e];
  atomicAdd(&deg[dst], 1);
}

// scan stage 1: per-block sums of CHUNK-sized chunks (coalesced)
__global__ __launch_bounds__(256) void scan_partial(const int* __restrict__ deg,
                                                    int* __restrict__ bsum, int N) {
  int base = blockIdx.x * CHUNK;
  int s = 0;
  for (int i = threadIdx.x; i < CHUNK; i += 256) {
    int g = base + i;
    if (g < N) s += deg[g];
  }
  __shared__ int red[256];
  red[threadIdx.x] = s;
  __syncthreads();
  for (int off = 128; off; off >>= 1) {
    if (threadIdx.x < off) red[threadIdx.x] += red[threadIdx.x + off];
    __syncthreads();
  }
  if (threadIdx.x == 0) bsum[blockIdx.x] = red[0];
}

// scan stage 2: single tiny block scans the <=256 block sums (exclusive, in place)
// also writes row_start[N] = total edge count
__global__ __launch_bounds__(256) void scan_bsum(int* __restrict__ bsum, int G,
                                                 int* __restrict__ row_end) {
  __shared__ int arr[256];
  int t = threadIdx.x;
  int v = (t < G) ? bsum[t] : 0;
  arr[t] = v;
  __syncthreads();
  for (int off = 1; off < 256; off <<= 1) {
    int u = (t >= off) ? arr[t - off] : 0;
    __syncthreads();
    arr[t] += u;
    __syncthreads();
  }
  if (t < G) bsum[t] = arr[t] - v;  // exclusive
  if (t == 255) *row_end = arr[255];
}

// scan stage 3: local scan of each chunk + block offset -> row_start, cursor
__global__ __launch_bounds__(256) void scan_final(const int* __restrict__ deg,
                                                  const int* __restrict__ bsum,
                                                  int* __restrict__ row_start,
                                                  int* __restrict__ cursor, int N) {
  int tid = threadIdx.x;
  int base = blockIdx.x * CHUNK + tid * 8;
  int d[8];
  int ts = 0;
#pragma unroll
  for (int j = 0; j < 8; ++j) {
    int g = base + j;
    int t = (g < N) ? deg[g] : 0;
    d[j] = ts;       // local exclusive prefix
    ts += t;
  }
  __shared__ int arr[256];
  arr[tid] = ts;
  __syncthreads();
  for (int off = 1; off < 256; off <<= 1) {
    int u = (tid >= off) ? arr[tid - off] : 0;
    __syncthreads();
    arr[tid] += u;
    __syncthreads();
  }
  int off0 = bsum[blockIdx.x] + arr[tid] - ts;
#pragma unroll
  for (int j = 0; j < 8; ++j) {
    int g = base + j;
    if (g < N) {
      int v = off0 + d[j];
      row_start[g] = v;
      cursor[g] = v;
    }
  }
}

__global__ void fill_kernel(const int* __restrict__ edges, int E,
                            int* __restrict__ cursor, int* __restrict__ csr_src) {
  int e = blockIdx.x * blockDim.x + threadIdx.x;
  if (e >= E) return;
  int src = edges[e];
  int dst = edges[(size_t)E + e];
  int pos = atomicAdd(&cursor[dst], 1);
  csr_src[pos] = src;
}

// ---------------- mean aggregation (pull, one wave per node) ----------------

__global__ __launch_bounds__(256) void agg_kernel(
    const float* __restrict__ xin, const int* __restrict__ row_start,
    const int* __restrict__ csr_src, float* __restrict__ agg, int N) {
  int wid = (blockIdx.x * blockDim.x + threadIdx.x) >> 6;
  int lane = threadIdx.x & 63;
  if (wid >= N) return;
  int r0 = row_start[wid];
  int r1 = row_start[wid + 1];
  float ax = 0.f, ay = 0.f;
  for (int base = r0; base < r1; base += 64) {
    int cnt = min(64, r1 - base);
    int idx = (lane < cnt) ? csr_src[base + lane] : 0;
    for (int j = 0; j < cnt; ++j) {
      int s = __shfl(idx, j);
      const float2 v = *reinterpret_cast<const float2*>(xin + (size_t)s * D + lane * 2);
      ax += v.x;
      ay += v.y;
    }
  }
  float inv = 1.0f / (float)max(r1 - r0, 1);
  float2 o;
  o.x = ax * inv;
  o.y = ay * inv;
  *reinterpret_cast<float2*>(agg + (size_t)wid * D + lane * 2) = o;
}

// ---------------- fused GEMM: out = normalize(agg@Wl + b + x@Wr), opt ReLU ----------------
// A = [agg | x] (K=256), B = [Wl ; Wr]. BM=128, BN=128, 8x8 per-thread micro-tile.
// Per-thread rows are tm + 16*i (wave's 4 tm values consecutive -> distinct LDS
// bank groups; rows 8 apart would alias since 8*68*4 == 0 mod 128).

__global__ __launch_bounds__(256) void sage_gemm_kernel(
    const float* __restrict__ agg, const float* __restrict__ xin,
    const float* __restrict__ Wl, const float* __restrict__ Wr,
    const float* __restrict__ bias, float* __restrict__ out,
    int N, int relu) {
  __shared__ float A_lds[128][68];  // 34.8 KB
  __shared__ float B_lds[64][128];  // 32 KB   -> 2 blocks/CU
  const int tid = threadIdx.x;
  const int tn = tid & 15;   // 16 col-groups of 8
  const int tm = tid >> 4;   // 16 row-groups (strided by 16)
  const int block_row = blockIdx.x * 128;

  float acc[8][8];
#pragma unroll
  for (int i = 0; i < 8; ++i)
#pragma unroll
    for (int j = 0; j < 8; ++j) acc[i][j] = 0.f;

  for (int kc = 0; kc < 4; ++kc) {
    __syncthreads();
    // stage A: 128 rows x 64 k of [agg|x]
#pragma unroll
    for (int t = 0; t < 8; ++t) {
      int f = tid + t * 256;     // 0..2047
      int row = f >> 4;          // 0..127
      int col = (f & 15) * 4;
      int gk = kc * 64 + col;
      int n = min(block_row + row, N - 1);
      const float* srcp = (gk < D) ? (agg + (size_t)n * D + gk)
                                   : (xin + (size_t)n * D + (gk - D));
      *reinterpret_cast<float4*>(&A_lds[row][col]) =
          *reinterpret_cast<const float4*>(srcp);
    }
    // stage B: 64 k-rows x 128 outs of [Wl;Wr]
#pragma unroll
    for (int t = 0; t < 8; ++t) {
      int f = tid + t * 256;
      int kk = f >> 5;
      int col = (f & 31) * 4;
      int gk = kc * 64 + kk;
      const float* srcp = (gk < D) ? (Wl + (size_t)gk * D + col)
                                   : (Wr + (size_t)(gk - D) * D + col);
      *reinterpret_cast<float4*>(&B_lds[kk][col]) =
          *reinterpret_cast<const float4*>(srcp);
    }
    __syncthreads();
#pragma unroll
    for (int k4 = 0; k4 < 16; ++k4) {
      float4 av[8];
#pragma unroll
      for (int i = 0; i < 8; ++i)
        av[i] = *reinterpret_cast<const float4*>(&A_lds[tm + 16 * i][k4 * 4]);
#pragma unroll
      for (int u = 0; u < 4; ++u) {
        float4 b0 = *reinterpret_cast<const float4*>(&B_lds[k4 * 4 + u][tn * 8]);
        float4 b1 = *reinterpret_cast<const float4*>(&B_lds[k4 * 4 + u][tn * 8 + 4]);
#pragma unroll
        for (int i = 0; i < 8; ++i) {
          float a = (u == 0) ? av[i].x : (u == 1) ? av[i].y : (u == 2) ? av[i].z
                                                                       : av[i].w;
          acc[i][0] += a * b0.x;
          acc[i][1] += a * b0.y;
          acc[i][2] += a * b0.z;
          acc[i][3] += a * b0.w;
          acc[i][4] += a * b1.x;
          acc[i][5] += a * b1.y;
          acc[i][6] += a * b1.z;
          acc[i][7] += a * b1.w;
        }
      }
    }
  }

  // epilogue: bias + row L2-normalize (row spread over 16 tn lanes) + optional ReLU
  float bv[8];
#pragma unroll
  for (int j = 0; j < 8; ++j) bv[j] = bias[tn * 8 + j];
#pragma unroll
  for (int i = 0; i < 8; ++i) {
    float v[8];
    float ss = 0.f;
#pragma unroll
    for (int j = 0; j < 8; ++j) {
      v[j] = acc[i][j] + bv[j];
      ss += v[j] * v[j];
    }
    ss += __shfl_xor(ss, 1);
    ss += __shfl_xor(ss, 2);
    ss += __shfl_xor(ss, 4);
    ss += __shfl_xor(ss, 8);
    float scale = 1.0f / fmaxf(sqrtf(ss), 1e-12f);
    int gn = block_row + tm + 16 * i;
    if (gn < N) {
      float o[8];
#pragma unroll
      for (int j = 0; j < 8; ++j) {
        o[j] = v[j] * scale;
        if (relu) o[j] = fmaxf(o[j], 0.f);
      }
      float4 w0, w1;
      w0.x = o[0]; w0.y = o[1]; w0.z = o[2]; w0.w = o[3];
      w1.x = o[4]; w1.y = o[5]; w1.z = o[6]; w1.w = o[7];
      float* dst = out + (size_t)gn * D + tn * 8;
      *reinterpret_cast<float4*>(dst) = w0;
      *reinterpret_cast<float4*>(dst + 4) = w1;
    }
  }
}

// ---------------- launch ----------------

extern "C" void kernel_launch(void* const* d_in, const int* in_sizes, int n_in,
                              void* d_out, int out_size, void* d_ws, size_t ws_size,
                              hipStream_t stream) {
  const float* x = (const float*)d_in[0];
  const int* edges = (const int*)d_in[1];
  const float* W1l = (const float*)d_in[2];
  const float* b1 = (const float*)d_in[3];
  const float* W1r = (const float*)d_in[4];
  const float* W2l = (const float*)d_in[5];
  const float* b2 = (const float*)d_in[6];
  const float* W2r = (const float*)d_in[7];
  float* out = (float*)d_out;

  const int N = in_sizes[0] / D;  // 100000
  const int E = in_sizes[1] / 2;  // 1600000
  const int G = (N + CHUNK - 1) / CHUNK;  // 49 (scan_bsum supports G<=256)

  char* ws = (char*)d_ws;
  float* agg = (float*)ws;                              // N*D f32 = 51.2 MB
  int* deg = (int*)(ws + (size_t)N * D * sizeof(float));
  int* row_start = deg + N;                             // N+1
  int* cursor = row_start + (N + 1);                    // N
  int* bsum = cursor + N;                               // G (<=256)
  int* csr_src = bsum + 256;                            // E

  hipMemsetAsync(deg, 0, (size_t)N * sizeof(int), stream);
  count_kernel<<<(E + 255) / 256, 256, 0, stream>>>(edges, E, deg);
  scan_partial<<<G, 256, 0, stream>>>(deg, bsum, N);
  scan_bsum<<<1, 256, 0, stream>>>(bsum, G, row_start + N);
  scan_final<<<G, 256, 0, stream>>>(deg, bsum, row_start, cursor, N);
  fill_kernel<<<(E + 255) / 256, 256, 0, stream>>>(edges, E, cursor, csr_src);

  // layer 1: h = relu(normalize(mean@W1l + b1 + x@W1r)) -> d_out (as scratch h)
  agg_kernel<<<(N + 3) / 4, 256, 0, stream>>>(x, row_start, csr_src, agg, N);
  sage_gemm_kernel<<<(N + 127) / 128, 256, 0, stream>>>(agg, x, W1l, W1r, b1, out, N, 1);

  // layer 2: out = normalize(mean(h)@W2l + b2 + h@W2r), in-place over h
  agg_kernel<<<(N + 3) / 4, 256, 0, stream>>>(out, row_start, csr_src, agg, N);
  sage_gemm_kernel<<<(N + 127) / 128, 256, 0, stream>>>(agg, out, W2l, W2r, b2, out, N, 0);
}

// Round 4
// 757.660 us; speedup vs baseline: 1.3787x; 1.2676x over previous
//
#include <hip/hip_runtime.h>

static constexpr int D = 128;
static constexpr int CHUNK = 2048;  // elements per block in the decomposed scan

// ---------------- CSR build ----------------
// Harness delivers integer inputs as int32 (edge_index is [2,E] int32).

__global__ void count_kernel(const int* __restrict__ edges, int E,
                             int* __restrict__ deg) {
  int e = blockIdx.x * blockDim.x + threadIdx.x;
  if (e >= E) return;
  int dst = edges[(size_t)E + e];
  atomicAdd(&deg[dst], 1);
}

__global__ __launch_bounds__(256) void scan_partial(const int* __restrict__ deg,
                                                    int* __restrict__ bsum, int N) {
  int base = blockIdx.x * CHUNK;
  int s = 0;
  for (int i = threadIdx.x; i < CHUNK; i += 256) {
    int g = base + i;
    if (g < N) s += deg[g];
  }
  __shared__ int red[256];
  red[threadIdx.x] = s;
  __syncthreads();
  for (int off = 128; off; off >>= 1) {
    if (threadIdx.x < off) red[threadIdx.x] += red[threadIdx.x + off];
    __syncthreads();
  }
  if (threadIdx.x == 0) bsum[blockIdx.x] = red[0];
}

__global__ __launch_bounds__(256) void scan_bsum(int* __restrict__ bsum, int G,
                                                 int* __restrict__ row_end) {
  __shared__ int arr[256];
  int t = threadIdx.x;
  int v = (t < G) ? bsum[t] : 0;
  arr[t] = v;
  __syncthreads();
  for (int off = 1; off < 256; off <<= 1) {
    int u = (t >= off) ? arr[t - off] : 0;
    __syncthreads();
    arr[t] += u;
    __syncthreads();
  }
  if (t < G) bsum[t] = arr[t] - v;  // exclusive
  if (t == 255) *row_end = arr[255];
}

__global__ __launch_bounds__(256) void scan_final(const int* __restrict__ deg,
                                                  const int* __restrict__ bsum,
                                                  int* __restrict__ row_start,
                                                  int* __restrict__ cursor, int N) {
  int tid = threadIdx.x;
  int base = blockIdx.x * CHUNK + tid * 8;
  int d[8];
  int ts = 0;
#pragma unroll
  for (int j = 0; j < 8; ++j) {
    int g = base + j;
    int t = (g < N) ? deg[g] : 0;
    d[j] = ts;
    ts += t;
  }
  __shared__ int arr[256];
  arr[tid] = ts;
  __syncthreads();
  for (int off = 1; off < 256; off <<= 1) {
    int u = (tid >= off) ? arr[tid - off] : 0;
    __syncthreads();
    arr[tid] += u;
    __syncthreads();
  }
  int off0 = bsum[blockIdx.x] + arr[tid] - ts;
#pragma unroll
  for (int j = 0; j < 8; ++j) {
    int g = base + j;
    if (g < N) {
      int v = off0 + d[j];
      row_start[g] = v;
      cursor[g] = v;
    }
  }
}

__global__ void fill_kernel(const int* __restrict__ edges, int E,
                            int* __restrict__ cursor, int* __restrict__ csr_src) {
  int e = blockIdx.x * blockDim.x + threadIdx.x;
  if (e >= E) return;
  int src = edges[e];
  int dst = edges[(size_t)E + e];
  int pos = atomicAdd(&cursor[dst], 1);
  csr_src[pos] = src;
}

// ---------------- mean aggregation (pull, one wave per node) ----------------

__global__ __launch_bounds__(256) void agg_kernel(
    const float* __restrict__ xin, const int* __restrict__ row_start,
    const int* __restrict__ csr_src, float* __restrict__ agg, int N) {
  int wid = (blockIdx.x * blockDim.x + threadIdx.x) >> 6;
  int lane = threadIdx.x & 63;
  if (wid >= N) return;
  int r0 = row_start[wid];
  int r1 = row_start[wid + 1];
  float ax = 0.f, ay = 0.f;
  for (int base = r0; base < r1; base += 64) {
    int cnt = min(64, r1 - base);
    int idx = (lane < cnt) ? csr_src[base + lane] : 0;
    for (int j = 0; j < cnt; ++j) {
      int s = __shfl(idx, j);
      const float2 v = *reinterpret_cast<const float2*>(xin + (size_t)s * D + lane * 2);
      ax += v.x;
      ay += v.y;
    }
  }
  float inv = 1.0f / (float)max(r1 - r0, 1);
  float2 o;
  o.x = ax * inv;
  o.y = ay * inv;
  *reinterpret_cast<float2*>(agg + (size_t)wid * D + lane * 2) = o;
}

// ---------------- fused GEMM: out = normalize(agg@Wl + b + x@Wr), opt ReLU ----------------
// A = [agg | x] (K=256), B = [Wl ; Wr]. BM=128, BN=128, BK=32, 8x8 micro-tile.
// LDS = 34.4 KB/block -> 4 blocks/CU; __launch_bounds__(256,4) caps VGPR<=128
// so 4 waves/SIMD are resident (occupancy was the round-3 limiter, not conflicts).

__global__ __launch_bounds__(256, 4) void sage_gemm_kernel(
    const float* __restrict__ agg, const float* __restrict__ xin,
    const float* __restrict__ Wl, const float* __restrict__ Wr,
    const float* __restrict__ bias, float* __restrict__ out,
    int N, int relu) {
  __shared__ float A_lds[128][36];  // stride 36 floats: rows 16 apart -> 2-way (free)
  __shared__ float B_lds[32][128];
  const int tid = threadIdx.x;
  const int tn = tid & 15;   // col-group (8 wide); within-wave for shuffle-reduce
  const int tm = tid >> 4;   // row-group; rows tm + 16*i
  const int block_row = blockIdx.x * 128;

  float acc[8][8];
#pragma unroll
  for (int i = 0; i < 8; ++i)
#pragma unroll
    for (int j = 0; j < 8; ++j) acc[i][j] = 0.f;

  for (int kc = 0; kc < 8; ++kc) {
    const float* Abase = (kc < 4) ? (agg + kc * 32) : (xin + (kc - 4) * 32);
    const float* Bbase = (kc < 4) ? (Wl + kc * 32 * D) : (Wr + (kc - 4) * 32 * D);
    __syncthreads();
    // stage A: 128 rows x 32 k
#pragma unroll
    for (int t = 0; t < 4; ++t) {
      int f = tid + t * 256;     // 0..1023
      int row = f >> 3;          // 0..127
      int col = (f & 7) * 4;     // 0..28
      int n = min(block_row + row, N - 1);
      *reinterpret_cast<float4*>(&A_lds[row][col]) =
          *reinterpret_cast<const float4*>(Abase + (size_t)n * D + col);
    }
    // stage B: 32 k-rows x 128 cols
#pragma unroll
    for (int t = 0; t < 4; ++t) {
      int f = tid + t * 256;
      int kk = f >> 5;           // 0..31
      int col = (f & 31) * 4;    // 0..124
      *reinterpret_cast<float4*>(&B_lds[kk][col]) =
          *reinterpret_cast<const float4*>(Bbase + (size_t)kk * D + col);
    }
    __syncthreads();
#pragma unroll
    for (int k4 = 0; k4 < 8; ++k4) {
      float4 av[8];
#pragma unroll
      for (int i = 0; i < 8; ++i)
        av[i] = *reinterpret_cast<const float4*>(&A_lds[tm + 16 * i][k4 * 4]);
#pragma unroll
      for (int u = 0; u < 4; ++u) {
        float4 b0 = *reinterpret_cast<const float4*>(&B_lds[k4 * 4 + u][tn * 8]);
        float4 b1 = *reinterpret_cast<const float4*>(&B_lds[k4 * 4 + u][tn * 8 + 4]);
#pragma unroll
        for (int i = 0; i < 8; ++i) {
          float a = (u == 0) ? av[i].x : (u == 1) ? av[i].y : (u == 2) ? av[i].z
                                                                       : av[i].w;
          acc[i][0] += a * b0.x;
          acc[i][1] += a * b0.y;
          acc[i][2] += a * b0.z;
          acc[i][3] += a * b0.w;
          acc[i][4] += a * b1.x;
          acc[i][5] += a * b1.y;
          acc[i][6] += a * b1.z;
          acc[i][7] += a * b1.w;
        }
      }
    }
  }

  // epilogue: bias + row L2-normalize (row spread over the 16 tn lanes) + ReLU
  float bv[8];
#pragma unroll
  for (int j = 0; j < 8; ++j) bv[j] = bias[tn * 8 + j];
#pragma unroll
  for (int i = 0; i < 8; ++i) {
    float v[8];
    float ss = 0.f;
#pragma unroll
    for (int j = 0; j < 8; ++j) {
      v[j] = acc[i][j] + bv[j];
      ss += v[j] * v[j];
    }
    ss += __shfl_xor(ss, 1);
    ss += __shfl_xor(ss, 2);
    ss += __shfl_xor(ss, 4);
    ss += __shfl_xor(ss, 8);
    float scale = 1.0f / fmaxf(sqrtf(ss), 1e-12f);
    int gn = block_row + tm + 16 * i;
    if (gn < N) {
      float o[8];
#pragma unroll
      for (int j = 0; j < 8; ++j) {
        o[j] = v[j] * scale;
        if (relu) o[j] = fmaxf(o[j], 0.f);
      }
      float4 w0, w1;
      w0.x = o[0]; w0.y = o[1]; w0.z = o[2]; w0.w = o[3];
      w1.x = o[4]; w1.y = o[5]; w1.z = o[6]; w1.w = o[7];
      float* dst = out + (size_t)gn * D + tn * 8;
      *reinterpret_cast<float4*>(dst) = w0;
      *reinterpret_cast<float4*>(dst + 4) = w1;
    }
  }
}

// ---------------- launch ----------------

extern "C" void kernel_launch(void* const* d_in, const int* in_sizes, int n_in,
                              void* d_out, int out_size, void* d_ws, size_t ws_size,
                              hipStream_t stream) {
  const float* x = (const float*)d_in[0];
  const int* edges = (const int*)d_in[1];
  const float* W1l = (const float*)d_in[2];
  const float* b1 = (const float*)d_in[3];
  const float* W1r = (const float*)d_in[4];
  const float* W2l = (const float*)d_in[5];
  const float* b2 = (const float*)d_in[6];
  const float* W2r = (const float*)d_in[7];
  float* out = (float*)d_out;

  const int N = in_sizes[0] / D;  // 100000
  const int E = in_sizes[1] / 2;  // 1600000
  const int G = (N + CHUNK - 1) / CHUNK;  // 49

  char* ws = (char*)d_ws;
  float* agg = (float*)ws;                              // N*D f32 = 51.2 MB
  int* deg = (int*)(ws + (size_t)N * D * sizeof(float));
  int* row_start = deg + N;                             // N+1
  int* cursor = row_start + (N + 1);                    // N
  int* bsum = cursor + N;                               // <=256
  int* csr_src = bsum + 256;                            // E

  hipMemsetAsync(deg, 0, (size_t)N * sizeof(int), stream);
  count_kernel<<<(E + 255) / 256, 256, 0, stream>>>(edges, E, deg);
  scan_partial<<<G, 256, 0, stream>>>(deg, bsum, N);
  scan_bsum<<<1, 256, 0, stream>>>(bsum, G, row_start + N);
  scan_final<<<G, 256, 0, stream>>>(deg, bsum, row_start, cursor, N);
  fill_kernel<<<(E + 255) / 256, 256, 0, stream>>>(edges, E, cursor, csr_src);

  // layer 1: h = relu(normalize(mean@W1l + b1 + x@W1r)) -> d_out (as scratch h)
  agg_kernel<<<(N + 3) / 4, 256, 0, stream>>>(x, row_start, csr_src, agg, N);
  sage_gemm_kernel<<<(N + 127) / 128, 256, 0, stream>>>(agg, x, W1l, W1r, b1, out, N, 1);

  // layer 2: out = normalize(mean(h)@W2l + b2 + h@W2r), in-place over h
  agg_kernel<<<(N + 3) / 4, 256, 0, stream>>>(out, row_start, csr_src, agg, N);
  sage_gemm_kernel<<<(N + 127) / 128, 256, 0, stream>>>(agg, out, W2l, W2r, b2, out, N, 0);
}

// Round 5
// 573.747 us; speedup vs baseline: 1.8206x; 1.3205x over previous
//
#include <hip/hip_runtime.h>

static constexpr int D = 128;
static constexpr int CHUNK = 2048;

typedef __attribute__((ext_vector_type(8))) short short8;
typedef __attribute__((ext_vector_type(4))) float f32x4;

__device__ inline ushort f2bf(float f) {
  union { float f; uint u; } x; x.f = f;
  uint r = (x.u + 0x7fffu + ((x.u >> 16) & 1u)) >> 16;  // RNE
  return (ushort)r;
}
__device__ inline float bf2f(uint lo16) {  // lo16 in low bits
  union { uint u; float f; } x; x.u = lo16 << 16;
  return x.f;
}

// ---------------- CSR build ----------------

__global__ void count_kernel(const int* __restrict__ edges, int E,
                             int* __restrict__ deg) {
  int e = blockIdx.x * blockDim.x + threadIdx.x;
  if (e >= E) return;
  atomicAdd(&deg[edges[(size_t)E + e]], 1);
}

__global__ __launch_bounds__(256) void scan_partial(const int* __restrict__ deg,
                                                    int* __restrict__ bsum, int N) {
  int base = blockIdx.x * CHUNK;
  int s = 0;
  for (int i = threadIdx.x; i < CHUNK; i += 256) {
    int g = base + i;
    if (g < N) s += deg[g];
  }
  __shared__ int red[256];
  red[threadIdx.x] = s;
  __syncthreads();
  for (int off = 128; off; off >>= 1) {
    if (threadIdx.x < off) red[threadIdx.x] += red[threadIdx.x + off];
    __syncthreads();
  }
  if (threadIdx.x == 0) bsum[blockIdx.x] = red[0];
}

__global__ __launch_bounds__(256) void scan_bsum(int* __restrict__ bsum, int G,
                                                 int* __restrict__ row_end) {
  __shared__ int arr[256];
  int t = threadIdx.x;
  int v = (t < G) ? bsum[t] : 0;
  arr[t] = v;
  __syncthreads();
  for (int off = 1; off < 256; off <<= 1) {
    int u = (t >= off) ? arr[t - off] : 0;
    __syncthreads();
    arr[t] += u;
    __syncthreads();
  }
  if (t < G) bsum[t] = arr[t] - v;
  if (t == 255) *row_end = arr[255];
}

__global__ __launch_bounds__(256) void scan_final(const int* __restrict__ deg,
                                                  const int* __restrict__ bsum,
                                                  int* __restrict__ row_start,
                                                  int* __restrict__ cursor, int N) {
  int tid = threadIdx.x;
  int base = blockIdx.x * CHUNK + tid * 8;
  int d[8];
  int ts = 0;
#pragma unroll
  for (int j = 0; j < 8; ++j) {
    int g = base + j;
    int t = (g < N) ? deg[g] : 0;
    d[j] = ts;
    ts += t;
  }
  __shared__ int arr[256];
  arr[tid] = ts;
  __syncthreads();
  for (int off = 1; off < 256; off <<= 1) {
    int u = (tid >= off) ? arr[tid - off] : 0;
    __syncthreads();
    arr[tid] += u;
    __syncthreads();
  }
  int off0 = bsum[blockIdx.x] + arr[tid] - ts;
#pragma unroll
  for (int j = 0; j < 8; ++j) {
    int g = base + j;
    if (g < N) {
      int v = off0 + d[j];
      row_start[g] = v;
      cursor[g] = v;
    }
  }
}

__global__ void fill_kernel(const int* __restrict__ edges, int E,
                            int* __restrict__ cursor, int* __restrict__ csr_src) {
  int e = blockIdx.x * blockDim.x + threadIdx.x;
  if (e >= E) return;
  int src = edges[e];
  int dst = edges[(size_t)E + e];
  int pos = atomicAdd(&cursor[dst], 1);
  csr_src[pos] = src;
}

// ---------------- bf16 conversions ----------------

__global__ __launch_bounds__(256) void cvt_bf16(const float* __restrict__ in,
                                                ushort* __restrict__ outb, int n8) {
  int i = blockIdx.x * blockDim.x + threadIdx.x;
  if (i >= n8) return;
  float4 a = *reinterpret_cast<const float4*>(in + (size_t)i * 8);
  float4 b = *reinterpret_cast<const float4*>(in + (size_t)i * 8 + 4);
  union { ushort s[8]; short8 v; } o;
  o.s[0] = f2bf(a.x); o.s[1] = f2bf(a.y); o.s[2] = f2bf(a.z); o.s[3] = f2bf(a.w);
  o.s[4] = f2bf(b.x); o.s[5] = f2bf(b.y); o.s[6] = f2bf(b.z); o.s[7] = f2bf(b.w);
  *reinterpret_cast<short8*>(outb + (size_t)i * 8) = o.v;
}

// WT[n][k] = bf16(W[k][n]) ; one 128x128 matrix, grid 64x256
__global__ __launch_bounds__(256) void wprep(const float* __restrict__ W,
                                             ushort* __restrict__ WT) {
  int e = blockIdx.x * 256 + threadIdx.x;  // 0..16383
  int k = e >> 7, n = e & 127;
  WT[n * 128 + k] = f2bf(W[e]);
}

// ---------------- mean aggregation (pull, one wave per node, bf16 rows) --------

__global__ __launch_bounds__(256) void agg_kernel_bf16(
    const ushort* __restrict__ xb, const int* __restrict__ row_start,
    const int* __restrict__ csr_src, ushort* __restrict__ aggb, int N) {
  int wid = (blockIdx.x * blockDim.x + threadIdx.x) >> 6;
  int lane = threadIdx.x & 63;
  if (wid >= N) return;
  int r0 = row_start[wid];
  int r1 = row_start[wid + 1];
  float ax = 0.f, ay = 0.f;
  for (int base = r0; base < r1; base += 64) {
    int cnt = min(64, r1 - base);
    int idx = (lane < cnt) ? csr_src[base + lane] : 0;
    for (int j = 0; j < cnt; ++j) {
      int s = __shfl(idx, j);
      uint p = *reinterpret_cast<const uint*>(xb + (size_t)s * D + lane * 2);
      ax += bf2f(p & 0xffffu);
      ay += bf2f(p >> 16);
    }
  }
  float inv = 1.0f / (float)max(r1 - r0, 1);
  uint o = (uint)f2bf(ax * inv) | ((uint)f2bf(ay * inv) << 16);
  *reinterpret_cast<uint*>(aggb + (size_t)wid * D + lane * 2) = o;
}

// ---------------- MFMA GEMM: out = normalize(agg@Wl + b + self@Wr) [+ReLU] ----
// A = [aggb | selfb] (row-major bf16, K=256), B via WT (bf16, WT[n][k]).
// Block: 256 thr (4 waves), tile M=128 x N=128, BK=64, mfma_f32_16x16x32_bf16.
// Wave w owns rows w*32..w*32+31 (full 128-col width -> normalize reduce is
// intra-16-lane-group). LDS XOR swizzle (T2): 16B slot ^= (row&7).

__global__ __launch_bounds__(256) void sage_gemm_mfma(
    const ushort* __restrict__ Aagg, const ushort* __restrict__ Aself,
    const ushort* __restrict__ WTl, const ushort* __restrict__ WTr,
    const float* __restrict__ bias, float* __restrict__ outf,
    ushort* __restrict__ outb, int N, int relu) {
  __shared__ ushort A_lds[128 * 64];
  __shared__ ushort B_lds[128 * 64];
  const int tid = threadIdx.x;
  const int lane = tid & 63;
  const int wave = tid >> 6;
  const int block_row = blockIdx.x * 128;

  f32x4 acc[2][8];
#pragma unroll
  for (int i = 0; i < 2; ++i)
#pragma unroll
    for (int j = 0; j < 8; ++j) acc[i][j] = (f32x4){0.f, 0.f, 0.f, 0.f};

  for (int kc = 0; kc < 4; ++kc) {
    const ushort* Asrc = (kc < 2) ? Aagg : Aself;
    const ushort* Bsrc = (kc < 2) ? WTl : WTr;
    const int koff = (kc & 1) * 64;
    __syncthreads();
#pragma unroll
    for (int v = 0; v < 4; ++v) {
      int f = tid + v * 256;   // 0..1023
      int row = f >> 3;        // 0..127
      int slot = f & 7;        // 16B slot
      int sw = (slot ^ (row & 7)) * 8;
      int n = min(block_row + row, N - 1);
      *reinterpret_cast<short8*>(&A_lds[row * 64 + sw]) =
          *reinterpret_cast<const short8*>(Asrc + (size_t)n * D + koff + slot * 8);
      *reinterpret_cast<short8*>(&B_lds[row * 64 + sw]) =
          *reinterpret_cast<const short8*>(Bsrc + (size_t)row * D + koff + slot * 8);
    }
    __syncthreads();
#pragma unroll
    for (int s = 0; s < 2; ++s) {
      const int kb = lane >> 4;
      const int rsel = lane & 15;
      const int slot = s * 4 + kb;  // 0..7
      short8 a[2], b[8];
#pragma unroll
      for (int i = 0; i < 2; ++i) {
        int row = wave * 32 + i * 16 + rsel;
        a[i] = *reinterpret_cast<const short8*>(
            &A_lds[row * 64 + (slot ^ (row & 7)) * 8]);
      }
#pragma unroll
      for (int j = 0; j < 8; ++j) {
        int nr = j * 16 + rsel;
        b[j] = *reinterpret_cast<const short8*>(
            &B_lds[nr * 64 + (slot ^ (nr & 7)) * 8]);
      }
#pragma unroll
      for (int i = 0; i < 2; ++i)
#pragma unroll
        for (int j = 0; j < 8; ++j)
          acc[i][j] = __builtin_amdgcn_mfma_f32_16x16x32_bf16(a[i], b[j],
                                                              acc[i][j], 0, 0, 0);
    }
  }

  // epilogue: D-frag mapping: row = wave*32 + i*16 + (lane>>4)*4 + r, col = j*16 + (lane&15)
  const int g = lane >> 4;
  const int cl = lane & 15;
  float bvals[8];
#pragma unroll
  for (int j = 0; j < 8; ++j) bvals[j] = bias[j * 16 + cl];
#pragma unroll
  for (int i = 0; i < 2; ++i) {
#pragma unroll
    for (int r = 0; r < 4; ++r) {
      float v[8];
      float ss = 0.f;
#pragma unroll
      for (int j = 0; j < 8; ++j) {
        v[j] = acc[i][j][r] + bvals[j];
        ss += v[j] * v[j];
      }
      ss += __shfl_xor(ss, 1);
      ss += __shfl_xor(ss, 2);
      ss += __shfl_xor(ss, 4);
      ss += __shfl_xor(ss, 8);
      float scale = 1.0f / fmaxf(sqrtf(ss), 1e-12f);
      int grow = block_row + wave * 32 + i * 16 + g * 4 + r;
      if (grow < N) {
        if (outb) {
#pragma unroll
          for (int j = 0; j < 8; ++j) {
            float o = v[j] * scale;
            if (relu) o = fmaxf(o, 0.f);
            outb[(size_t)grow * D + j * 16 + cl] = f2bf(o);
          }
        } else {
#pragma unroll
          for (int j = 0; j < 8; ++j)
            outf[(size_t)grow * D + j * 16 + cl] = v[j] * scale;
        }
      }
    }
  }
}

// ---------------- launch ----------------

extern "C" void kernel_launch(void* const* d_in, const int* in_sizes, int n_in,
                              void* d_out, int out_size, void* d_ws, size_t ws_size,
                              hipStream_t stream) {
  const float* x = (const float*)d_in[0];
  const int* edges = (const int*)d_in[1];
  const float* W1l = (const float*)d_in[2];
  const float* b1 = (const float*)d_in[3];
  const float* W1r = (const float*)d_in[4];
  const float* W2l = (const float*)d_in[5];
  const float* b2 = (const float*)d_in[6];
  const float* W2r = (const float*)d_in[7];
  float* out = (float*)d_out;

  const int N = in_sizes[0] / D;  // 100000
  const int E = in_sizes[1] / 2;  // 1600000
  const int G = (N + CHUNK - 1) / CHUNK;

  char* ws = (char*)d_ws;
  ushort* xb   = (ushort*)ws;                 // N*D bf16 (also reused as h)
  ushort* aggb = xb + (size_t)N * D;          // N*D bf16
  ushort* wt1l = aggb + (size_t)N * D;        // 4 x 128*128 bf16
  ushort* wt1r = wt1l + D * D;
  ushort* wt2l = wt1r + D * D;
  ushort* wt2r = wt2l + D * D;
  int* deg = (int*)(wt2r + D * D);
  int* row_start = deg + N;                   // N+1
  int* cursor = row_start + (N + 1);
  int* bsum = cursor + N;                     // <=256
  int* csr_src = bsum + 256;                  // E

  hipMemsetAsync(deg, 0, (size_t)N * sizeof(int), stream);
  count_kernel<<<(E + 255) / 256, 256, 0, stream>>>(edges, E, deg);
  scan_partial<<<G, 256, 0, stream>>>(deg, bsum, N);
  scan_bsum<<<1, 256, 0, stream>>>(bsum, G, row_start + N);
  scan_final<<<G, 256, 0, stream>>>(deg, bsum, row_start, cursor, N);
  fill_kernel<<<(E + 255) / 256, 256, 0, stream>>>(edges, E, cursor, csr_src);

  cvt_bf16<<<(N * D / 8 + 255) / 256, 256, 0, stream>>>(x, xb, N * D / 8);
  wprep<<<64, 256, 0, stream>>>(W1l, wt1l);
  wprep<<<64, 256, 0, stream>>>(W1r, wt1r);
  wprep<<<64, 256, 0, stream>>>(W2l, wt2l);
  wprep<<<64, 256, 0, stream>>>(W2r, wt2r);

  // layer 1: h(bf16, in-place over xb) = relu(normalize(mean@W1l + b1 + x@W1r))
  agg_kernel_bf16<<<(N + 3) / 4, 256, 0, stream>>>(xb, row_start, csr_src, aggb, N);
  sage_gemm_mfma<<<(N + 127) / 128, 256, 0, stream>>>(aggb, xb, wt1l, wt1r, b1,
                                                      nullptr, xb, N, 1);

  // layer 2: out(f32) = normalize(mean(h)@W2l + b2 + h@W2r)
  agg_kernel_bf16<<<(N + 3) / 4, 256, 0, stream>>>(xb, row_start, csr_src, aggb, N);
  sage_gemm_mfma<<<(N + 127) / 128, 256, 0, stream>>>(aggb, xb, wt2l, wt2r, b2,
                                                      out, nullptr, N, 0);
}

// Round 6
// 442.487 us; speedup vs baseline: 2.3607x; 1.2966x over previous
//
#include <hip/hip_runtime.h>

static constexpr int D = 128;
static constexpr int CHUNK = 2048;  // scan chunk over N
static constexpr int EB = 4096;     // edges per bin_scatter block
static constexpr int BSH = 8;       // 256 dst-nodes per bucket

typedef __attribute__((ext_vector_type(8))) short short8;
typedef __attribute__((ext_vector_type(4))) float f32x4;

__device__ inline ushort f2bf(float f) {
  union { float f; uint u; } x; x.f = f;
  uint r = (x.u + 0x7fffu + ((x.u >> 16) & 1u)) >> 16;  // RNE
  return (ushort)r;
}
__device__ inline float bf2f(uint lo16) {
  union { uint u; float f; } x; x.u = lo16 << 16;
  return x.f;
}

// ---------------- binned CSR build ----------------
// Buckets of 256 consecutive dst nodes. packed edge = src (17b) | dstlocal<<17 (8b).

__global__ __launch_bounds__(256) void bucket_hist_kernel(
    const int* __restrict__ dsts, int E, int NB, int* __restrict__ bhist) {
  __shared__ int h[512];
  for (int i = threadIdx.x; i < NB; i += 256) h[i] = 0;
  __syncthreads();
  int base = blockIdx.x * EB;
  for (int t = threadIdx.x; t < EB; t += 256) {
    int e = base + t;
    if (e < E) atomicAdd(&h[dsts[e] >> BSH], 1);
  }
  __syncthreads();
  for (int i = threadIdx.x; i < NB; i += 256)
    if (h[i]) atomicAdd(&bhist[i], h[i]);
}

__global__ __launch_bounds__(512) void bucket_scan_kernel(
    const int* __restrict__ bhist, int NB, int* __restrict__ bstart,
    int* __restrict__ bcursor) {
  __shared__ int arr[512];
  int t = threadIdx.x;
  int v = (t < NB) ? bhist[t] : 0;
  arr[t] = v;
  __syncthreads();
  for (int off = 1; off < 512; off <<= 1) {
    int u = (t >= off) ? arr[t - off] : 0;
    __syncthreads();
    arr[t] += u;
    __syncthreads();
  }
  if (t < NB) {
    int s = arr[t] - v;
    bstart[t] = s;
    bcursor[t] = s;
  }
  if (t == NB - 1) bstart[NB] = arr[t];
}

// per-block LDS hist -> one global reserve per (block,bucket) -> direct scatter.
// Same-line writes now come from one CU within one chunk window -> L2 coalesces.
__global__ __launch_bounds__(256) void bin_scatter_kernel(
    const int* __restrict__ srcs, const int* __restrict__ dsts, int E, int NB,
    int* __restrict__ bcursor, uint* __restrict__ bucket_arr) {
  __shared__ int h[512];
  __shared__ int gpos[512];
  __shared__ int run[512];
  for (int i = threadIdx.x; i < NB; i += 256) { h[i] = 0; run[i] = 0; }
  __syncthreads();
  int base = blockIdx.x * EB;
  for (int t = threadIdx.x; t < EB; t += 256) {
    int e = base + t;
    if (e < E) atomicAdd(&h[dsts[e] >> BSH], 1);
  }
  __syncthreads();
  for (int i = threadIdx.x; i < NB; i += 256)
    gpos[i] = h[i] ? atomicAdd(&bcursor[i], h[i]) : 0;
  __syncthreads();
  for (int t = threadIdx.x; t < EB; t += 256) {
    int e = base + t;
    if (e < E) {
      int dst = dsts[e];
      int src = srcs[e];
      int b = dst >> BSH;
      int r = atomicAdd(&run[b], 1);
      bucket_arr[gpos[b] + r] = (uint)src | ((uint)(dst & 255) << 17);
    }
  }
}

// per-bucket degree from packed entries (replaces global random-atomic count)
__global__ __launch_bounds__(256) void bucket_deg_kernel(
    const uint* __restrict__ bucket_arr, const int* __restrict__ bstart,
    int* __restrict__ deg, int N) {
  __shared__ int dcnt[256];
  int b = blockIdx.x;
  int n0 = b << BSH;
  int nn = min(256, N - n0);
  if (threadIdx.x < nn) dcnt[threadIdx.x] = 0;
  __syncthreads();
  int s = bstart[b], e = bstart[b + 1];
  for (int t = s + threadIdx.x; t < e; t += 256)
    atomicAdd(&dcnt[bucket_arr[t] >> 17], 1);
  __syncthreads();
  if (threadIdx.x < nn) deg[n0 + threadIdx.x] = dcnt[threadIdx.x];
}

// one block per bucket: 16KB contiguous csr window, LDS cursors, full-line writes
__global__ __launch_bounds__(256) void csr_scatter_kernel(
    const uint* __restrict__ bucket_arr, const int* __restrict__ bstart,
    const int* __restrict__ row_start, int* __restrict__ csr_src, int N) {
  __shared__ int cur[256];
  int b = blockIdx.x;
  int n0 = b << BSH;
  int nn = min(256, N - n0);
  if (threadIdx.x < nn) cur[threadIdx.x] = row_start[n0 + threadIdx.x];
  __syncthreads();
  int s = bstart[b], e = bstart[b + 1];
  for (int t = s + threadIdx.x; t < e; t += 256) {
    uint p = bucket_arr[t];
    int pos = atomicAdd(&cur[p >> 17], 1);
    csr_src[pos] = (int)(p & 0x1FFFFu);
  }
}

// ---------------- scan over deg -> row_start ----------------

__global__ __launch_bounds__(256) void scan_partial(const int* __restrict__ deg,
                                                    int* __restrict__ bsum, int N) {
  int base = blockIdx.x * CHUNK;
  int s = 0;
  for (int i = threadIdx.x; i < CHUNK; i += 256) {
    int g = base + i;
    if (g < N) s += deg[g];
  }
  __shared__ int red[256];
  red[threadIdx.x] = s;
  __syncthreads();
  for (int off = 128; off; off >>= 1) {
    if (threadIdx.x < off) red[threadIdx.x] += red[threadIdx.x + off];
    __syncthreads();
  }
  if (threadIdx.x == 0) bsum[blockIdx.x] = red[0];
}

__global__ __launch_bounds__(256) void scan_bsum(int* __restrict__ bsum, int G,
                                                 int* __restrict__ row_end) {
  __shared__ int arr[256];
  int t = threadIdx.x;
  int v = (t < G) ? bsum[t] : 0;
  arr[t] = v;
  __syncthreads();
  for (int off = 1; off < 256; off <<= 1) {
    int u = (t >= off) ? arr[t - off] : 0;
    __syncthreads();
    arr[t] += u;
    __syncthreads();
  }
  if (t < G) bsum[t] = arr[t] - v;
  if (t == 255) *row_end = arr[255];
}

__global__ __launch_bounds__(256) void scan_final(const int* __restrict__ deg,
                                                  const int* __restrict__ bsum,
                                                  int* __restrict__ row_start, int N) {
  int tid = threadIdx.x;
  int base = blockIdx.x * CHUNK + tid * 8;
  int d[8];
  int ts = 0;
#pragma unroll
  for (int j = 0; j < 8; ++j) {
    int g = base + j;
    int t = (g < N) ? deg[g] : 0;
    d[j] = ts;
    ts += t;
  }
  __shared__ int arr[256];
  arr[tid] = ts;
  __syncthreads();
  for (int off = 1; off < 256; off <<= 1) {
    int u = (tid >= off) ? arr[tid - off] : 0;
    __syncthreads();
    arr[tid] += u;
    __syncthreads();
  }
  int off0 = bsum[blockIdx.x] + arr[tid] - ts;
#pragma unroll
  for (int j = 0; j < 8; ++j) {
    int g = base + j;
    if (g < N) row_start[g] = off0 + d[j];
  }
}

// ---------------- bf16 conversions ----------------

__global__ __launch_bounds__(256) void cvt_bf16(const float* __restrict__ in,
                                                ushort* __restrict__ outb, int n8) {
  int i = blockIdx.x * blockDim.x + threadIdx.x;
  if (i >= n8) return;
  float4 a = *reinterpret_cast<const float4*>(in + (size_t)i * 8);
  float4 b = *reinterpret_cast<const float4*>(in + (size_t)i * 8 + 4);
  union { ushort s[8]; short8 v; } o;
  o.s[0] = f2bf(a.x); o.s[1] = f2bf(a.y); o.s[2] = f2bf(a.z); o.s[3] = f2bf(a.w);
  o.s[4] = f2bf(b.x); o.s[5] = f2bf(b.y); o.s[6] = f2bf(b.z); o.s[7] = f2bf(b.w);
  *reinterpret_cast<short8*>(outb + (size_t)i * 8) = o.v;
}

__global__ __launch_bounds__(256) void wprep(const float* __restrict__ W,
                                             ushort* __restrict__ WT) {
  int e = blockIdx.x * 256 + threadIdx.x;
  int k = e >> 7, n = e & 127;
  WT[n * 128 + k] = f2bf(W[e]);
}

// ---------------- mean aggregation (pull, one wave per node, bf16 rows) --------

__global__ __launch_bounds__(256) void agg_kernel_bf16(
    const ushort* __restrict__ xb, const int* __restrict__ row_start,
    const int* __restrict__ csr_src, ushort* __restrict__ aggb, int N) {
  int wid = (blockIdx.x * blockDim.x + threadIdx.x) >> 6;
  int lane = threadIdx.x & 63;
  if (wid >= N) return;
  int r0 = row_start[wid];
  int r1 = row_start[wid + 1];
  float ax = 0.f, ay = 0.f;
  for (int base = r0; base < r1; base += 64) {
    int cnt = min(64, r1 - base);
    int idx = (lane < cnt) ? csr_src[base + lane] : 0;
    for (int j = 0; j < cnt; ++j) {
      int s = __shfl(idx, j);
      uint p = *reinterpret_cast<const uint*>(xb + (size_t)s * D + lane * 2);
      ax += bf2f(p & 0xffffu);
      ay += bf2f(p >> 16);
    }
  }
  float inv = 1.0f / (float)max(r1 - r0, 1);
  uint o = (uint)f2bf(ax * inv) | ((uint)f2bf(ay * inv) << 16);
  *reinterpret_cast<uint*>(aggb + (size_t)wid * D + lane * 2) = o;
}

// ---------------- MFMA GEMM (unchanged from round 5) ----------------

__global__ __launch_bounds__(256) void sage_gemm_mfma(
    const ushort* __restrict__ Aagg, const ushort* __restrict__ Aself,
    const ushort* __restrict__ WTl, const ushort* __restrict__ WTr,
    const float* __restrict__ bias, float* __restrict__ outf,
    ushort* __restrict__ outb, int N, int relu) {
  __shared__ ushort A_lds[128 * 64];
  __shared__ ushort B_lds[128 * 64];
  const int tid = threadIdx.x;
  const int lane = tid & 63;
  const int wave = tid >> 6;
  const int block_row = blockIdx.x * 128;

  f32x4 acc[2][8];
#pragma unroll
  for (int i = 0; i < 2; ++i)
#pragma unroll
    for (int j = 0; j < 8; ++j) acc[i][j] = (f32x4){0.f, 0.f, 0.f, 0.f};

  for (int kc = 0; kc < 4; ++kc) {
    const ushort* Asrc = (kc < 2) ? Aagg : Aself;
    const ushort* Bsrc = (kc < 2) ? WTl : WTr;
    const int koff = (kc & 1) * 64;
    __syncthreads();
#pragma unroll
    for (int v = 0; v < 4; ++v) {
      int f = tid + v * 256;
      int row = f >> 3;
      int slot = f & 7;
      int sw = (slot ^ (row & 7)) * 8;
      int n = min(block_row + row, N - 1);
      *reinterpret_cast<short8*>(&A_lds[row * 64 + sw]) =
          *reinterpret_cast<const short8*>(Asrc + (size_t)n * D + koff + slot * 8);
      *reinterpret_cast<short8*>(&B_lds[row * 64 + sw]) =
          *reinterpret_cast<const short8*>(Bsrc + (size_t)row * D + koff + slot * 8);
    }
    __syncthreads();
#pragma unroll
    for (int s = 0; s < 2; ++s) {
      const int kb = lane >> 4;
      const int rsel = lane & 15;
      const int slot = s * 4 + kb;
      short8 a[2], b[8];
#pragma unroll
      for (int i = 0; i < 2; ++i) {
        int row = wave * 32 + i * 16 + rsel;
        a[i] = *reinterpret_cast<const short8*>(
            &A_lds[row * 64 + (slot ^ (row & 7)) * 8]);
      }
#pragma unroll
      for (int j = 0; j < 8; ++j) {
        int nr = j * 16 + rsel;
        b[j] = *reinterpret_cast<const short8*>(
            &B_lds[nr * 64 + (slot ^ (nr & 7)) * 8]);
      }
#pragma unroll
      for (int i = 0; i < 2; ++i)
#pragma unroll
        for (int j = 0; j < 8; ++j)
          acc[i][j] = __builtin_amdgcn_mfma_f32_16x16x32_bf16(a[i], b[j],
                                                              acc[i][j], 0, 0, 0);
    }
  }

  const int g = lane >> 4;
  const int cl = lane & 15;
  float bvals[8];
#pragma unroll
  for (int j = 0; j < 8; ++j) bvals[j] = bias[j * 16 + cl];
#pragma unroll
  for (int i = 0; i < 2; ++i) {
#pragma unroll
    for (int r = 0; r < 4; ++r) {
      float v[8];
      float ss = 0.f;
#pragma unroll
      for (int j = 0; j < 8; ++j) {
        v[j] = acc[i][j][r] + bvals[j];
        ss += v[j] * v[j];
      }
      ss += __shfl_xor(ss, 1);
      ss += __shfl_xor(ss, 2);
      ss += __shfl_xor(ss, 4);
      ss += __shfl_xor(ss, 8);
      float scale = 1.0f / fmaxf(sqrtf(ss), 1e-12f);
      int grow = block_row + wave * 32 + i * 16 + g * 4 + r;
      if (grow < N) {
        if (outb) {
#pragma unroll
          for (int j = 0; j < 8; ++j) {
            float o = v[j] * scale;
            if (relu) o = fmaxf(o, 0.f);
            outb[(size_t)grow * D + j * 16 + cl] = f2bf(o);
          }
        } else {
#pragma unroll
          for (int j = 0; j < 8; ++j)
            outf[(size_t)grow * D + j * 16 + cl] = v[j] * scale;
        }
      }
    }
  }
}

// ---------------- launch ----------------

extern "C" void kernel_launch(void* const* d_in, const int* in_sizes, int n_in,
                              void* d_out, int out_size, void* d_ws, size_t ws_size,
                              hipStream_t stream) {
  const float* x = (const float*)d_in[0];
  const int* edges = (const int*)d_in[1];
  const float* W1l = (const float*)d_in[2];
  const float* b1 = (const float*)d_in[3];
  const float* W1r = (const float*)d_in[4];
  const float* W2l = (const float*)d_in[5];
  const float* b2 = (const float*)d_in[6];
  const float* W2r = (const float*)d_in[7];
  float* out = (float*)d_out;

  const int N = in_sizes[0] / D;       // 100000
  const int E = in_sizes[1] / 2;       // 1600000
  const int G = (N + CHUNK - 1) / CHUNK;
  const int NB = (N + 255) >> BSH;     // 391 buckets
  const int GE = (E + EB - 1) / EB;    // 391 edge chunks

  const int* srcs = edges;
  const int* dsts = edges + E;

  char* ws = (char*)d_ws;
  ushort* xb   = (ushort*)ws;                 // N*D bf16 (also reused as h)
  ushort* aggb = xb + (size_t)N * D;          // N*D bf16
  ushort* wt1l = aggb + (size_t)N * D;
  ushort* wt1r = wt1l + D * D;
  ushort* wt2l = wt1r + D * D;
  ushort* wt2r = wt2l + D * D;
  int* deg = (int*)(wt2r + D * D);
  int* row_start = deg + N;                   // N+1
  int* bsum = row_start + (N + 1);            // 256
  int* bhist = bsum + 256;                    // 512
  int* bstart = bhist + 512;                  // 513
  int* bcursor = bstart + 513;                // 512
  int* csr_src = bcursor + 512;               // E
  uint* bucket_arr = (uint*)aggb;             // aliases aggb (pre-agg only)

  hipMemsetAsync(bhist, 0, 512 * sizeof(int), stream);
  bucket_hist_kernel<<<GE, 256, 0, stream>>>(dsts, E, NB, bhist);
  bucket_scan_kernel<<<1, 512, 0, stream>>>(bhist, NB, bstart, bcursor);
  bin_scatter_kernel<<<GE, 256, 0, stream>>>(srcs, dsts, E, NB, bcursor, bucket_arr);
  bucket_deg_kernel<<<NB, 256, 0, stream>>>(bucket_arr, bstart, deg, N);
  scan_partial<<<G, 256, 0, stream>>>(deg, bsum, N);
  scan_bsum<<<1, 256, 0, stream>>>(bsum, G, row_start + N);
  scan_final<<<G, 256, 0, stream>>>(deg, bsum, row_start, N);
  csr_scatter_kernel<<<NB, 256, 0, stream>>>(bucket_arr, bstart, row_start,
                                             csr_src, N);

  cvt_bf16<<<(N * D / 8 + 255) / 256, 256, 0, stream>>>(x, xb, N * D / 8);
  wprep<<<64, 256, 0, stream>>>(W1l, wt1l);
  wprep<<<64, 256, 0, stream>>>(W1r, wt1r);
  wprep<<<64, 256, 0, stream>>>(W2l, wt2l);
  wprep<<<64, 256, 0, stream>>>(W2r, wt2r);

  // layer 1: h(bf16, in-place over xb) = relu(normalize(mean@W1l + b1 + x@W1r))
  agg_kernel_bf16<<<(N + 3) / 4, 256, 0, stream>>>(xb, row_start, csr_src, aggb, N);
  sage_gemm_mfma<<<(N + 127) / 128, 256, 0, stream>>>(aggb, xb, wt1l, wt1r, b1,
                                                      nullptr, xb, N, 1);

  // layer 2: out(f32) = normalize(mean(h)@W2l + b2 + h@W2r)
  agg_kernel_bf16<<<(N + 3) / 4, 256, 0, stream>>>(xb, row_start, csr_src, aggb, N);
  sage_gemm_mfma<<<(N + 127) / 128, 256, 0, stream>>>(aggb, xb, wt2l, wt2r, b2,
                                                      out, nullptr, N, 0);
}

// Round 7
// 354.852 us; speedup vs baseline: 2.9437x; 1.2470x over previous
//
#include <hip/hip_runtime.h>

static constexpr int D = 128;
static constexpr int CHUNK = 2048;  // scan chunk over N
static constexpr int EB = 4096;     // edges per bin_scatter block
static constexpr int BSH = 8;       // 256 dst-nodes per bucket

typedef __attribute__((ext_vector_type(8))) short short8;
typedef __attribute__((ext_vector_type(4))) float f32x4;

__device__ inline ushort f2bf(float f) {
  union { float f; uint u; } x; x.f = f;
  uint r = (x.u + 0x7fffu + ((x.u >> 16) & 1u)) >> 16;  // RNE
  return (ushort)r;
}
__device__ inline float bfhi(uint u) {  // high 16 bits as bf16 -> f32
  union { uint u; float f; } x; x.u = u & 0xffff0000u;
  return x.f;
}
__device__ inline float bflo(uint u) {  // low 16 bits as bf16 -> f32
  union { uint u; float f; } x; x.u = u << 16;
  return x.f;
}

// ---------------- binned CSR build ----------------

__global__ __launch_bounds__(256) void bucket_hist_kernel(
    const int* __restrict__ dsts, int E, int NB, int* __restrict__ bhist) {
  __shared__ int h[512];
  for (int i = threadIdx.x; i < NB; i += 256) h[i] = 0;
  __syncthreads();
  int base = blockIdx.x * EB;
  for (int t = threadIdx.x; t < EB; t += 256) {
    int e = base + t;
    if (e < E) atomicAdd(&h[dsts[e] >> BSH], 1);
  }
  __syncthreads();
  for (int i = threadIdx.x; i < NB; i += 256)
    if (h[i]) atomicAdd(&bhist[i], h[i]);
}

__global__ __launch_bounds__(512) void bucket_scan_kernel(
    const int* __restrict__ bhist, int NB, int* __restrict__ bstart,
    int* __restrict__ bcursor) {
  __shared__ int arr[512];
  int t = threadIdx.x;
  int v = (t < NB) ? bhist[t] : 0;
  arr[t] = v;
  __syncthreads();
  for (int off = 1; off < 512; off <<= 1) {
    int u = (t >= off) ? arr[t - off] : 0;
    __syncthreads();
    arr[t] += u;
    __syncthreads();
  }
  if (t < NB) {
    int s = arr[t] - v;
    bstart[t] = s;
    bcursor[t] = s;
  }
  if (t == NB - 1) bstart[NB] = arr[t];
}

__global__ __launch_bounds__(256) void bin_scatter_kernel(
    const int* __restrict__ srcs, const int* __restrict__ dsts, int E, int NB,
    int* __restrict__ bcursor, uint* __restrict__ bucket_arr) {
  __shared__ int h[512];
  __shared__ int gpos[512];
  __shared__ int run[512];
  for (int i = threadIdx.x; i < NB; i += 256) { h[i] = 0; run[i] = 0; }
  __syncthreads();
  int base = blockIdx.x * EB;
  for (int t = threadIdx.x; t < EB; t += 256) {
    int e = base + t;
    if (e < E) atomicAdd(&h[dsts[e] >> BSH], 1);
  }
  __syncthreads();
  for (int i = threadIdx.x; i < NB; i += 256)
    gpos[i] = h[i] ? atomicAdd(&bcursor[i], h[i]) : 0;
  __syncthreads();
  for (int t = threadIdx.x; t < EB; t += 256) {
    int e = base + t;
    if (e < E) {
      int dst = dsts[e];
      int src = srcs[e];
      int b = dst >> BSH;
      int r = atomicAdd(&run[b], 1);
      bucket_arr[gpos[b] + r] = (uint)src | ((uint)(dst & 255) << 17);
    }
  }
}

__global__ __launch_bounds__(256) void bucket_deg_kernel(
    const uint* __restrict__ bucket_arr, const int* __restrict__ bstart,
    int* __restrict__ deg, int N) {
  __shared__ int dcnt[256];
  int b = blockIdx.x;
  int n0 = b << BSH;
  int nn = min(256, N - n0);
  if (threadIdx.x < nn) dcnt[threadIdx.x] = 0;
  __syncthreads();
  int s = bstart[b], e = bstart[b + 1];
  for (int t = s + threadIdx.x; t < e; t += 256)
    atomicAdd(&dcnt[bucket_arr[t] >> 17], 1);
  __syncthreads();
  if (threadIdx.x < nn) deg[n0 + threadIdx.x] = dcnt[threadIdx.x];
}

__global__ __launch_bounds__(256) void csr_scatter_kernel(
    const uint* __restrict__ bucket_arr, const int* __restrict__ bstart,
    const int* __restrict__ row_start, int* __restrict__ csr_src, int N) {
  __shared__ int cur[256];
  int b = blockIdx.x;
  int n0 = b << BSH;
  int nn = min(256, N - n0);
  if (threadIdx.x < nn) cur[threadIdx.x] = row_start[n0 + threadIdx.x];
  __syncthreads();
  int s = bstart[b], e = bstart[b + 1];
  for (int t = s + threadIdx.x; t < e; t += 256) {
    uint p = bucket_arr[t];
    int pos = atomicAdd(&cur[p >> 17], 1);
    csr_src[pos] = (int)(p & 0x1FFFFu);
  }
}

// ---------------- scan over deg -> row_start ----------------

__global__ __launch_bounds__(256) void scan_partial(const int* __restrict__ deg,
                                                    int* __restrict__ bsum, int N) {
  int base = blockIdx.x * CHUNK;
  int s = 0;
  for (int i = threadIdx.x; i < CHUNK; i += 256) {
    int g = base + i;
    if (g < N) s += deg[g];
  }
  __shared__ int red[256];
  red[threadIdx.x] = s;
  __syncthreads();
  for (int off = 128; off; off >>= 1) {
    if (threadIdx.x < off) red[threadIdx.x] += red[threadIdx.x + off];
    __syncthreads();
  }
  if (threadIdx.x == 0) bsum[blockIdx.x] = red[0];
}

__global__ __launch_bounds__(256) void scan_bsum(int* __restrict__ bsum, int G,
                                                 int* __restrict__ row_end) {
  __shared__ int arr[256];
  int t = threadIdx.x;
  int v = (t < G) ? bsum[t] : 0;
  arr[t] = v;
  __syncthreads();
  for (int off = 1; off < 256; off <<= 1) {
    int u = (t >= off) ? arr[t - off] : 0;
    __syncthreads();
    arr[t] += u;
    __syncthreads();
  }
  if (t < G) bsum[t] = arr[t] - v;
  if (t == 255) *row_end = arr[255];
}

__global__ __launch_bounds__(256) void scan_final(const int* __restrict__ deg,
                                                  const int* __restrict__ bsum,
                                                  int* __restrict__ row_start, int N) {
  int tid = threadIdx.x;
  int base = blockIdx.x * CHUNK + tid * 8;
  int d[8];
  int ts = 0;
#pragma unroll
  for (int j = 0; j < 8; ++j) {
    int g = base + j;
    int t = (g < N) ? deg[g] : 0;
    d[j] = ts;
    ts += t;
  }
  __shared__ int arr[256];
  arr[tid] = ts;
  __syncthreads();
  for (int off = 1; off < 256; off <<= 1) {
    int u = (tid >= off) ? arr[tid - off] : 0;
    __syncthreads();
    arr[tid] += u;
    __syncthreads();
  }
  int off0 = bsum[blockIdx.x] + arr[tid] - ts;
#pragma unroll
  for (int j = 0; j < 8; ++j) {
    int g = base + j;
    if (g < N) row_start[g] = off0 + d[j];
  }
}

// ---------------- bf16 conversions ----------------

__global__ __launch_bounds__(256) void cvt_bf16(const float* __restrict__ in,
                                                ushort* __restrict__ outb, int n8) {
  int i = blockIdx.x * blockDim.x + threadIdx.x;
  if (i >= n8) return;
  float4 a = *reinterpret_cast<const float4*>(in + (size_t)i * 8);
  float4 b = *reinterpret_cast<const float4*>(in + (size_t)i * 8 + 4);
  union { ushort s[8]; short8 v; } o;
  o.s[0] = f2bf(a.x); o.s[1] = f2bf(a.y); o.s[2] = f2bf(a.z); o.s[3] = f2bf(a.w);
  o.s[4] = f2bf(b.x); o.s[5] = f2bf(b.y); o.s[6] = f2bf(b.z); o.s[7] = f2bf(b.w);
  *reinterpret_cast<short8*>(outb + (size_t)i * 8) = o.v;
}

__global__ __launch_bounds__(256) void wprep(const float* __restrict__ W,
                                             ushort* __restrict__ WT) {
  int e = blockIdx.x * 256 + threadIdx.x;
  int k = e >> 7, n = e & 127;
  WT[n * 128 + k] = f2bf(W[e]);
}

// ---------------- mean aggregation v2 ----------------
// One wave per node. 16-lane group g handles neighbor j+g; lane loads uint4
// (16 B) of that row -> one global_load_dwordx4 covers 4 rows (1024 B); the
// 16-neighbor step issues 4 independent dwordx4 loads -> >=4 gathers in
// flight per wave (round-6 limiter: VGPR=12, ~1 load in flight).

#define ACC8(P, M)                                   \
  acc[0] += (M) * bflo(P.x); acc[1] += (M) * bfhi(P.x); \
  acc[2] += (M) * bflo(P.y); acc[3] += (M) * bfhi(P.y); \
  acc[4] += (M) * bflo(P.z); acc[5] += (M) * bfhi(P.z); \
  acc[6] += (M) * bflo(P.w); acc[7] += (M) * bfhi(P.w);

__global__ __launch_bounds__(256) void agg_kernel_bf16(
    const ushort* __restrict__ xb, const int* __restrict__ row_start,
    const int* __restrict__ csr_src, ushort* __restrict__ aggb, int N) {
  int wid = (blockIdx.x * blockDim.x + threadIdx.x) >> 6;
  int lane = threadIdx.x & 63;
  if (wid >= N) return;
  int r0 = row_start[wid];
  int r1 = row_start[wid + 1];
  const int grp = lane >> 4;   // which neighbor within a 4-batch
  const int sub = lane & 15;   // 16B slice within the row
  float acc[8];
#pragma unroll
  for (int k = 0; k < 8; ++k) acc[k] = 0.f;

  for (int base = r0; base < r1; base += 64) {
    int cnt = min(64, r1 - base);
    int idx = (lane < cnt) ? csr_src[base + lane] : 0;
    for (int j = 0; j < cnt; j += 16) {
      int s0 = __shfl(idx, j + grp);
      int s1 = __shfl(idx, j + 4 + grp);
      int s2 = __shfl(idx, j + 8 + grp);
      int s3 = __shfl(idx, j + 12 + grp);
      float m0 = (j + grp < cnt) ? 1.f : 0.f;
      float m1 = (j + 4 + grp < cnt) ? 1.f : 0.f;
      float m2 = (j + 8 + grp < cnt) ? 1.f : 0.f;
      float m3 = (j + 12 + grp < cnt) ? 1.f : 0.f;
      uint4 p0 = *reinterpret_cast<const uint4*>(xb + (size_t)s0 * D + sub * 8);
      uint4 p1 = *reinterpret_cast<const uint4*>(xb + (size_t)s1 * D + sub * 8);
      uint4 p2 = *reinterpret_cast<const uint4*>(xb + (size_t)s2 * D + sub * 8);
      uint4 p3 = *reinterpret_cast<const uint4*>(xb + (size_t)s3 * D + sub * 8);
      ACC8(p0, m0)
      ACC8(p1, m1)
      ACC8(p2, m2)
      ACC8(p3, m3)
    }
  }
  // sum the 4 neighbor-groups (lanes l, l+16, l+32, l+48 share sub)
#pragma unroll
  for (int k = 0; k < 8; ++k) {
    acc[k] += __shfl_xor(acc[k], 16);
    acc[k] += __shfl_xor(acc[k], 32);
  }
  float inv = 1.0f / (float)max(r1 - r0, 1);
  if (grp == 0) {
    union { ushort s[8]; short8 v; } o;
#pragma unroll
    for (int k = 0; k < 8; ++k) o.s[k] = f2bf(acc[k] * inv);
    *reinterpret_cast<short8*>(aggb + (size_t)wid * D + sub * 8) = o.v;
  }
}

// ---------------- MFMA GEMM (unchanged) ----------------

__global__ __launch_bounds__(256) void sage_gemm_mfma(
    const ushort* __restrict__ Aagg, const ushort* __restrict__ Aself,
    const ushort* __restrict__ WTl, const ushort* __restrict__ WTr,
    const float* __restrict__ bias, float* __restrict__ outf,
    ushort* __restrict__ outb, int N, int relu) {
  __shared__ ushort A_lds[128 * 64];
  __shared__ ushort B_lds[128 * 64];
  const int tid = threadIdx.x;
  const int lane = tid & 63;
  const int wave = tid >> 6;
  const int block_row = blockIdx.x * 128;

  f32x4 acc[2][8];
#pragma unroll
  for (int i = 0; i < 2; ++i)
#pragma unroll
    for (int j = 0; j < 8; ++j) acc[i][j] = (f32x4){0.f, 0.f, 0.f, 0.f};

  for (int kc = 0; kc < 4; ++kc) {
    const ushort* Asrc = (kc < 2) ? Aagg : Aself;
    const ushort* Bsrc = (kc < 2) ? WTl : WTr;
    const int koff = (kc & 1) * 64;
    __syncthreads();
#pragma unroll
    for (int v = 0; v < 4; ++v) {
      int f = tid + v * 256;
      int row = f >> 3;
      int slot = f & 7;
      int sw = (slot ^ (row & 7)) * 8;
      int n = min(block_row + row, N - 1);
      *reinterpret_cast<short8*>(&A_lds[row * 64 + sw]) =
          *reinterpret_cast<const short8*>(Asrc + (size_t)n * D + koff + slot * 8);
      *reinterpret_cast<short8*>(&B_lds[row * 64 + sw]) =
          *reinterpret_cast<const short8*>(Bsrc + (size_t)row * D + koff + slot * 8);
    }
    __syncthreads();
#pragma unroll
    for (int s = 0; s < 2; ++s) {
      const int kb = lane >> 4;
      const int rsel = lane & 15;
      const int slot = s * 4 + kb;
      short8 a[2], b[8];
#pragma unroll
      for (int i = 0; i < 2; ++i) {
        int row = wave * 32 + i * 16 + rsel;
        a[i] = *reinterpret_cast<const short8*>(
            &A_lds[row * 64 + (slot ^ (row & 7)) * 8]);
      }
#pragma unroll
      for (int j = 0; j < 8; ++j) {
        int nr = j * 16 + rsel;
        b[j] = *reinterpret_cast<const short8*>(
            &B_lds[nr * 64 + (slot ^ (nr & 7)) * 8]);
      }
#pragma unroll
      for (int i = 0; i < 2; ++i)
#pragma unroll
        for (int j = 0; j < 8; ++j)
          acc[i][j] = __builtin_amdgcn_mfma_f32_16x16x32_bf16(a[i], b[j],
                                                              acc[i][j], 0, 0, 0);
    }
  }

  const int g = lane >> 4;
  const int cl = lane & 15;
  float bvals[8];
#pragma unroll
  for (int j = 0; j < 8; ++j) bvals[j] = bias[j * 16 + cl];
#pragma unroll
  for (int i = 0; i < 2; ++i) {
#pragma unroll
    for (int r = 0; r < 4; ++r) {
      float v[8];
      float ss = 0.f;
#pragma unroll
      for (int j = 0; j < 8; ++j) {
        v[j] = acc[i][j][r] + bvals[j];
        ss += v[j] * v[j];
      }
      ss += __shfl_xor(ss, 1);
      ss += __shfl_xor(ss, 2);
      ss += __shfl_xor(ss, 4);
      ss += __shfl_xor(ss, 8);
      float scale = 1.0f / fmaxf(sqrtf(ss), 1e-12f);
      int grow = block_row + wave * 32 + i * 16 + g * 4 + r;
      if (grow < N) {
        if (outb) {
#pragma unroll
          for (int j = 0; j < 8; ++j) {
            float o = v[j] * scale;
            if (relu) o = fmaxf(o, 0.f);
            outb[(size_t)grow * D + j * 16 + cl] = f2bf(o);
          }
        } else {
#pragma unroll
          for (int j = 0; j < 8; ++j)
            outf[(size_t)grow * D + j * 16 + cl] = v[j] * scale;
        }
      }
    }
  }
}

// ---------------- launch ----------------

extern "C" void kernel_launch(void* const* d_in, const int* in_sizes, int n_in,
                              void* d_out, int out_size, void* d_ws, size_t ws_size,
                              hipStream_t stream) {
  const float* x = (const float*)d_in[0];
  const int* edges = (const int*)d_in[1];
  const float* W1l = (const float*)d_in[2];
  const float* b1 = (const float*)d_in[3];
  const float* W1r = (const float*)d_in[4];
  const float* W2l = (const float*)d_in[5];
  const float* b2 = (const float*)d_in[6];
  const float* W2r = (const float*)d_in[7];
  float* out = (float*)d_out;

  const int N = in_sizes[0] / D;       // 100000
  const int E = in_sizes[1] / 2;       // 1600000
  const int G = (N + CHUNK - 1) / CHUNK;
  const int NB = (N + 255) >> BSH;     // 391 buckets
  const int GE = (E + EB - 1) / EB;    // 391 edge chunks

  const int* srcs = edges;
  const int* dsts = edges + E;

  char* ws = (char*)d_ws;
  ushort* xb   = (ushort*)ws;                 // N*D bf16 (reused as h)
  ushort* aggb = xb + (size_t)N * D;          // N*D bf16
  ushort* wt1l = aggb + (size_t)N * D;
  ushort* wt1r = wt1l + D * D;
  ushort* wt2l = wt1r + D * D;
  ushort* wt2r = wt2l + D * D;
  int* deg = (int*)(wt2r + D * D);
  int* row_start = deg + N;                   // N+1
  int* bsum = row_start + (N + 1);            // 256
  int* bhist = bsum + 256;                    // 512
  int* bstart = bhist + 512;                  // 513
  int* bcursor = bstart + 513;                // 512
  int* csr_src = bcursor + 512;               // E
  uint* bucket_arr = (uint*)aggb;             // aliases aggb (pre-agg only)

  hipMemsetAsync(bhist, 0, 512 * sizeof(int), stream);
  bucket_hist_kernel<<<GE, 256, 0, stream>>>(dsts, E, NB, bhist);
  bucket_scan_kernel<<<1, 512, 0, stream>>>(bhist, NB, bstart, bcursor);
  bin_scatter_kernel<<<GE, 256, 0, stream>>>(srcs, dsts, E, NB, bcursor, bucket_arr);
  bucket_deg_kernel<<<NB, 256, 0, stream>>>(bucket_arr, bstart, deg, N);
  scan_partial<<<G, 256, 0, stream>>>(deg, bsum, N);
  scan_bsum<<<1, 256, 0, stream>>>(bsum, G, row_start + N);
  scan_final<<<G, 256, 0, stream>>>(deg, bsum, row_start, N);
  csr_scatter_kernel<<<NB, 256, 0, stream>>>(bucket_arr, bstart, row_start,
                                             csr_src, N);

  cvt_bf16<<<(N * D / 8 + 255) / 256, 256, 0, stream>>>(x, xb, N * D / 8);
  wprep<<<64, 256, 0, stream>>>(W1l, wt1l);
  wprep<<<64, 256, 0, stream>>>(W1r, wt1r);
  wprep<<<64, 256, 0, stream>>>(W2l, wt2l);
  wprep<<<64, 256, 0, stream>>>(W2r, wt2r);

  // layer 1: h(bf16, in-place over xb) = relu(normalize(mean@W1l + b1 + x@W1r))
  agg_kernel_bf16<<<(N + 3) / 4, 256, 0, stream>>>(xb, row_start, csr_src, aggb, N);
  sage_gemm_mfma<<<(N + 127) / 128, 256, 0, stream>>>(aggb, xb, wt1l, wt1r, b1,
                                                      nullptr, xb, N, 1);

  // layer 2: out(f32) = normalize(mean(h)@W2l + b2 + h@W2r)
  agg_kernel_bf16<<<(N + 3) / 4, 256, 0, stream>>>(xb, row_start, csr_src, aggb, N);
  sage_gemm_mfma<<<(N + 127) / 128, 256, 0, stream>>>(aggb, xb, wt2l, wt2r, b2,
                                                      out, nullptr, N, 0);
}

// Round 9
// 328.728 us; speedup vs baseline: 3.1776x; 1.0795x over previous
//
#include <hip/hip_runtime.h>

static constexpr int D = 128;
static constexpr int EB = 4096;     // edges per bin_scatter block
static constexpr int BSH = 8;       // 256 dst-nodes per bucket

typedef __attribute__((ext_vector_type(8))) short short8;
typedef __attribute__((ext_vector_type(4))) float f32x4;

__device__ inline ushort f2bf(float f) {
  union { float f; uint u; } x; x.f = f;
  uint r = (x.u + 0x7fffu + ((x.u >> 16) & 1u)) >> 16;  // RNE
  return (ushort)r;
}
__device__ inline float bfhi(uint u) {
  union { uint u; float f; } x; x.u = u & 0xffff0000u;
  return x.f;
}
__device__ inline float bflo(uint u) {
  union { uint u; float f; } x; x.u = u << 16;
  return x.f;
}

#define GLOAD_LDS16(g, l)                                                  \
  __builtin_amdgcn_global_load_lds(                                        \
      (const __attribute__((address_space(1))) void*)(g),                  \
      (__attribute__((address_space(3))) void*)(l), 16, 0, 0)

// ---------------- binned CSR build ----------------

__global__ __launch_bounds__(256) void bucket_hist_kernel(
    const int* __restrict__ dsts, int E, int NB, int* __restrict__ bhist) {
  __shared__ int h[512];
  for (int i = threadIdx.x; i < NB; i += 256) h[i] = 0;
  __syncthreads();
  int base = blockIdx.x * EB;
  for (int t = threadIdx.x; t < EB; t += 256) {
    int e = base + t;
    if (e < E) atomicAdd(&h[dsts[e] >> BSH], 1);
  }
  __syncthreads();
  for (int i = threadIdx.x; i < NB; i += 256)
    if (h[i]) atomicAdd(&bhist[i], h[i]);
}

__global__ __launch_bounds__(512) void bucket_scan_kernel(
    const int* __restrict__ bhist, int NB, int* __restrict__ bstart,
    int* __restrict__ bcursor) {
  __shared__ int arr[512];
  int t = threadIdx.x;
  int v = (t < NB) ? bhist[t] : 0;
  arr[t] = v;
  __syncthreads();
  for (int off = 1; off < 512; off <<= 1) {
    int u = (t >= off) ? arr[t - off] : 0;
    __syncthreads();
    arr[t] += u;
    __syncthreads();
  }
  if (t < NB) {
    int s = arr[t] - v;
    bstart[t] = s;
    bcursor[t] = s;
  }
  if (t == NB - 1) bstart[NB] = arr[t];
}

__global__ __launch_bounds__(256) void bin_scatter_kernel(
    const int* __restrict__ srcs, const int* __restrict__ dsts, int E, int NB,
    int* __restrict__ bcursor, uint* __restrict__ bucket_arr) {
  __shared__ int h[512];
  __shared__ int gpos[512];
  __shared__ int run[512];
  for (int i = threadIdx.x; i < NB; i += 256) { h[i] = 0; run[i] = 0; }
  __syncthreads();
  int base = blockIdx.x * EB;
  for (int t = threadIdx.x; t < EB; t += 256) {
    int e = base + t;
    if (e < E) atomicAdd(&h[dsts[e] >> BSH], 1);
  }
  __syncthreads();
  for (int i = threadIdx.x; i < NB; i += 256)
    gpos[i] = h[i] ? atomicAdd(&bcursor[i], h[i]) : 0;
  __syncthreads();
  for (int t = threadIdx.x; t < EB; t += 256) {
    int e = base + t;
    if (e < E) {
      int dst = dsts[e];
      int src = srcs[e];
      int b = dst >> BSH;
      int r = atomicAdd(&run[b], 1);
      bucket_arr[gpos[b] + r] = (uint)src | ((uint)(dst & 255) << 17);
    }
  }
}

// Fused: per-bucket degree hist -> local 256-scan (row_start = bstart[b] +
// local prefix, valid because buckets are 256 CONSECUTIVE nodes) -> LDS-cursor
// scatter into csr_src. Replaces bucket_deg + 3-kernel global scan +
// csr_scatter (saves 4 dispatches + 2 full edge-array passes + deg array).
__global__ __launch_bounds__(256) void csr_fused_kernel(
    const uint* __restrict__ bucket_arr, const int* __restrict__ bstart,
    int* __restrict__ row_start, int* __restrict__ csr_src, int N, int NB) {
  __shared__ int arr[256];
  __shared__ int cur[256];
  int b = blockIdx.x;
  int t = threadIdx.x;
  int n0 = b << BSH;
  int nn = min(256, N - n0);
  arr[t] = 0;
  __syncthreads();
  int s = bstart[b], e = bstart[b + 1];
  for (int i = s + t; i < e; i += 256)
    atomicAdd(&arr[bucket_arr[i] >> 17], 1);
  __syncthreads();
  int v = arr[t];
  __syncthreads();
  // inclusive scan
  int run = v;
  arr[t] = run;
  __syncthreads();
  for (int off = 1; off < 256; off <<= 1) {
    int u = (t >= off) ? arr[t - off] : 0;
    __syncthreads();
    arr[t] += u;
    __syncthreads();
  }
  int rs = bstart[b] + arr[t] - v;  // exclusive prefix + bucket base
  cur[t] = rs;
  if (t < nn) row_start[n0 + t] = rs;
  if (b == NB - 1 && t == 0) row_start[N] = bstart[NB];
  __syncthreads();
  for (int i = s + t; i < e; i += 256) {
    uint p = bucket_arr[i];
    int pos = atomicAdd(&cur[p >> 17], 1);
    csr_src[pos] = (int)(p & 0x1FFFFu);
  }
}

// ---------------- bf16 conversions ----------------

__global__ __launch_bounds__(256) void cvt_bf16(const float* __restrict__ in,
                                                ushort* __restrict__ outb, int n8) {
  int i = blockIdx.x * blockDim.x + threadIdx.x;
  if (i >= n8) return;
  float4 a = *reinterpret_cast<const float4*>(in + (size_t)i * 8);
  float4 b = *reinterpret_cast<const float4*>(in + (size_t)i * 8 + 4);
  union { ushort s[8]; short8 v; } o;
  o.s[0] = f2bf(a.x); o.s[1] = f2bf(a.y); o.s[2] = f2bf(a.z); o.s[3] = f2bf(a.w);
  o.s[4] = f2bf(b.x); o.s[5] = f2bf(b.y); o.s[6] = f2bf(b.z); o.s[7] = f2bf(b.w);
  *reinterpret_cast<short8*>(outb + (size_t)i * 8) = o.v;
}

// all 4 weights in one launch: grid 256, w = bid>>6; WT[w][n][k] = bf16(W[k][n])
__global__ __launch_bounds__(256) void wprep_all(
    const float* __restrict__ W1l, const float* __restrict__ W1r,
    const float* __restrict__ W2l, const float* __restrict__ W2r,
    ushort* __restrict__ wt) {
  int w = blockIdx.x >> 6;
  const float* W = (w == 0) ? W1l : (w == 1) ? W1r : (w == 2) ? W2l : W2r;
  int e = (blockIdx.x & 63) * 256 + threadIdx.x;  // 0..16383
  int k = e >> 7, n = e & 127;
  wt[w * D * D + n * 128 + k] = f2bf(W[e]);
}

// ---------------- mean aggregation (wave per node, 4 rows per load batch) ----

#define ACC8(P, M)                                      \
  acc[0] += (M) * bflo(P.x); acc[1] += (M) * bfhi(P.x); \
  acc[2] += (M) * bflo(P.y); acc[3] += (M) * bfhi(P.y); \
  acc[4] += (M) * bflo(P.z); acc[5] += (M) * bfhi(P.z); \
  acc[6] += (M) * bflo(P.w); acc[7] += (M) * bfhi(P.w);

__global__ __launch_bounds__(256) void agg_kernel_bf16(
    const ushort* __restrict__ xb, const int* __restrict__ row_start,
    const int* __restrict__ csr_src, ushort* __restrict__ aggb, int N) {
  int wid = (blockIdx.x * blockDim.x + threadIdx.x) >> 6;
  int lane = threadIdx.x & 63;
  if (wid >= N) return;
  int r0 = row_start[wid];
  int r1 = row_start[wid + 1];
  const int grp = lane >> 4;
  const int sub = lane & 15;
  const uint loff = (uint)(sub << 4);  // byte offset of this lane's 16B slice
  const char* xc = (const char*)xb;    // 25.6 MB buffer: 32-bit offsets suffice
  float acc[8];
#pragma unroll
  for (int k = 0; k < 8; ++k) acc[k] = 0.f;

  for (int base = r0; base < r1; base += 64) {
    int cnt = min(64, r1 - base);
    int idx = (lane < cnt) ? csr_src[base + lane] : 0;
    for (int j = 0; j < cnt; j += 16) {
      uint o0 = ((uint)__shfl(idx, j + grp) << 8) + loff;
      uint o1 = ((uint)__shfl(idx, j + 4 + grp) << 8) + loff;
      uint o2 = ((uint)__shfl(idx, j + 8 + grp) << 8) + loff;
      uint o3 = ((uint)__shfl(idx, j + 12 + grp) << 8) + loff;
      float m0 = (j + grp < cnt) ? 1.f : 0.f;
      float m1 = (j + 4 + grp < cnt) ? 1.f : 0.f;
      float m2 = (j + 8 + grp < cnt) ? 1.f : 0.f;
      float m3 = (j + 12 + grp < cnt) ? 1.f : 0.f;
      uint4 p0 = *reinterpret_cast<const uint4*>(xc + o0);
      uint4 p1 = *reinterpret_cast<const uint4*>(xc + o1);
      uint4 p2 = *reinterpret_cast<const uint4*>(xc + o2);
      uint4 p3 = *reinterpret_cast<const uint4*>(xc + o3);
      ACC8(p0, m0)
      ACC8(p1, m1)
      ACC8(p2, m2)
      ACC8(p3, m3)
    }
  }
#pragma unroll
  for (int k = 0; k < 8; ++k) {
    acc[k] += __shfl_xor(acc[k], 16);
    acc[k] += __shfl_xor(acc[k], 32);
  }
  float inv = 1.0f / (float)max(r1 - r0, 1);
  if (grp == 0) {
    union { ushort s[8]; short8 v; } o;
#pragma unroll
    for (int k = 0; k < 8; ++k) o.s[k] = f2bf(acc[k] * inv);
    *reinterpret_cast<short8*>(aggb + (size_t)wid * D + sub * 8) = o.v;
  }
}

// ---------------- MFMA GEMM: out = normalize(agg@Wl + b + self@Wr) [+ReLU] ----
// Staging via global_load_lds (linear LDS dest + inverse-swizzled global
// source; XOR swizzle is an involution so the physical layout — and thus all
// reads — are unchanged from round 5's verified kernel).

__global__ __launch_bounds__(256) void sage_gemm_mfma(
    const ushort* __restrict__ Aagg, const ushort* __restrict__ Aself,
    const ushort* __restrict__ WTl, const ushort* __restrict__ WTr,
    const float* __restrict__ bias, float* __restrict__ outf,
    ushort* __restrict__ outb, int N, int relu) {
  __shared__ ushort A_lds[128 * 64];
  __shared__ ushort B_lds[128 * 64];
  const int tid = threadIdx.x;
  const int lane = tid & 63;
  const int wave = tid >> 6;
  const int block_row = blockIdx.x * 128;

  f32x4 acc[2][8];
#pragma unroll
  for (int i = 0; i < 2; ++i)
#pragma unroll
    for (int j = 0; j < 8; ++j) acc[i][j] = (f32x4){0.f, 0.f, 0.f, 0.f};

  for (int kc = 0; kc < 4; ++kc) {
    const ushort* Asrc = (kc < 2) ? Aagg : Aself;
    const ushort* Bsrc = (kc < 2) ? WTl : WTr;
    const int koff = (kc & 1) * 64;
    __syncthreads();
#pragma unroll
    for (int v = 0; v < 4; ++v) {
      int f = tid + v * 256;
      int row = f >> 3;
      int slot = f & 7;
      int gs = slot ^ (row & 7);  // inverse swizzle on the SOURCE side
      int n = min(block_row + row, N - 1);
      GLOAD_LDS16(Asrc + (size_t)n * D + koff + gs * 8,
                  &A_lds[row * 64 + slot * 8]);
      GLOAD_LDS16(Bsrc + (size_t)row * D + koff + gs * 8,
                  &B_lds[row * 64 + slot * 8]);
    }
    __syncthreads();
#pragma unroll
    for (int s = 0; s < 2; ++s) {
      const int kb = lane >> 4;
      const int rsel = lane & 15;
      const int slot = s * 4 + kb;
      short8 a[2], b[8];
#pragma unroll
      for (int i = 0; i < 2; ++i) {
        int row = wave * 32 + i * 16 + rsel;
        a[i] = *reinterpret_cast<const short8*>(
            &A_lds[row * 64 + (slot ^ (row & 7)) * 8]);
      }
#pragma unroll
      for (int j = 0; j < 8; ++j) {
        int nr = j * 16 + rsel;
        b[j] = *reinterpret_cast<const short8*>(
            &B_lds[nr * 64 + (slot ^ (nr & 7)) * 8]);
      }
#pragma unroll
      for (int i = 0; i < 2; ++i)
#pragma unroll
        for (int j = 0; j < 8; ++j)
          acc[i][j] = __builtin_amdgcn_mfma_f32_16x16x32_bf16(a[i], b[j],
                                                              acc[i][j], 0, 0, 0);
    }
  }

  const int g = lane >> 4;
  const int cl = lane & 15;
  float bvals[8];
#pragma unroll
  for (int j = 0; j < 8; ++j) bvals[j] = bias[j * 16 + cl];
#pragma unroll
  for (int i = 0; i < 2; ++i) {
#pragma unroll
    for (int r = 0; r < 4; ++r) {
      float v[8];
      float ss = 0.f;
#pragma unroll
      for (int j = 0; j < 8; ++j) {
        v[j] = acc[i][j][r] + bvals[j];
        ss += v[j] * v[j];
      }
      ss += __shfl_xor(ss, 1);
      ss += __shfl_xor(ss, 2);
      ss += __shfl_xor(ss, 4);
      ss += __shfl_xor(ss, 8);
      float scale = 1.0f / fmaxf(sqrtf(ss), 1e-12f);
      int grow = block_row + wave * 32 + i * 16 + g * 4 + r;
      if (grow < N) {
        if (outb) {
#pragma unroll
          for (int j = 0; j < 8; ++j) {
            float o = v[j] * scale;
            if (relu) o = fmaxf(o, 0.f);
            outb[(size_t)grow * D + j * 16 + cl] = f2bf(o);
          }
        } else {
#pragma unroll
          for (int j = 0; j < 8; ++j)
            outf[(size_t)grow * D + j * 16 + cl] = v[j] * scale;
        }
      }
    }
  }
}

// ---------------- launch ----------------

extern "C" void kernel_launch(void* const* d_in, const int* in_sizes, int n_in,
                              void* d_out, int out_size, void* d_ws, size_t ws_size,
                              hipStream_t stream) {
  const float* x = (const float*)d_in[0];
  const int* edges = (const int*)d_in[1];
  const float* W1l = (const float*)d_in[2];
  const float* b1 = (const float*)d_in[3];
  const float* W1r = (const float*)d_in[4];
  const float* W2l = (const float*)d_in[5];
  const float* b2 = (const float*)d_in[6];
  const float* W2r = (const float*)d_in[7];
  float* out = (float*)d_out;

  const int N = in_sizes[0] / D;       // 100000
  const int E = in_sizes[1] / 2;       // 1600000
  const int NB = (N + 255) >> BSH;     // 391 buckets
  const int GE = (E + EB - 1) / EB;    // 391 edge chunks

  const int* srcs = edges;
  const int* dsts = edges + E;

  char* ws = (char*)d_ws;
  ushort* xb   = (ushort*)ws;                 // N*D bf16 (reused as h)
  ushort* aggb = xb + (size_t)N * D;          // N*D bf16
  ushort* wt   = aggb + (size_t)N * D;        // 4 x D*D bf16
  int* row_start = (int*)(wt + 4 * D * D);    // N+1
  int* bhist = row_start + (N + 1);           // 512
  int* bstart = bhist + 512;                  // 513
  int* bcursor = bstart + 513;                // 512
  int* csr_src = bcursor + 512;               // E
  uint* bucket_arr = (uint*)aggb;             // aliases aggb (pre-agg only)

  hipMemsetAsync(bhist, 0, 512 * sizeof(int), stream);
  bucket_hist_kernel<<<GE, 256, 0, stream>>>(dsts, E, NB, bhist);
  bucket_scan_kernel<<<1, 512, 0, stream>>>(bhist, NB, bstart, bcursor);
  bin_scatter_kernel<<<GE, 256, 0, stream>>>(srcs, dsts, E, NB, bcursor, bucket_arr);
  csr_fused_kernel<<<NB, 256, 0, stream>>>(bucket_arr, bstart, row_start,
                                           csr_src, N, NB);

  cvt_bf16<<<(N * D / 8 + 255) / 256, 256, 0, stream>>>(x, xb, N * D / 8);
  wprep_all<<<256, 256, 0, stream>>>(W1l, W1r, W2l, W2r, wt);

  ushort* wt1l = wt;
  ushort* wt1r = wt + D * D;
  ushort* wt2l = wt + 2 * D * D;
  ushort* wt2r = wt + 3 * D * D;

  // layer 1: h(bf16, in-place over xb) = relu(normalize(mean@W1l + b1 + x@W1r))
  agg_kernel_bf16<<<(N + 3) / 4, 256, 0, stream>>>(xb, row_start, csr_src, aggb, N);
  sage_gemm_mfma<<<(N + 127) / 128, 256, 0, stream>>>(aggb, xb, wt1l, wt1r, b1,
                                                      nullptr, xb, N, 1);

  // layer 2: out(f32) = normalize(mean(h)@W2l + b2 + h@W2r)
  agg_kernel_bf16<<<(N + 3) / 4, 256, 0, stream>>>(xb, row_start, csr_src, aggb, N);
  sage_gemm_mfma<<<(N + 127) / 128, 256, 0, stream>>>(aggb, xb, wt2l, wt2r, b2,
                                                      out, nullptr, N, 0);
}